// Round 6
// baseline (715.954 us; speedup 1.0000x reference)
//
#include <hip/hip_runtime.h>
#include <hip/hip_fp16.h>

// MessagePassingLayer, pull-based, bucketed LDS-atomic aggregation:
//  y = relu(x@Wm+bm) per NODE, fp16;
//  t = x@Wu[0:64]+bu per NODE, fp16 (x-half of the update GEMM, split so each
//      thread needs only wreg[64] -- wreg[128] provably spills to scratch);
//  partA: partition edge records (w|dloc|src packed in u64) into 782 buckets
//         of 128 nodes via LDS histogram + reserved ranges;
//  gather: one block per bucket, edge-parallel, LDS fp32 atomic accumulate
//          into lagg[128][64] (32KB), then mean + coalesced writeback -> d_out;
//  updB: out = l2norm(relu(t + agg@Wu[64:128])), in-place on d_out.

#define DIM 64
#define LOG_NPB 7
#define NPB 128             // nodes per bucket
#define CAP 2048            // record capacity per bucket (mean 1535, sigma 39)
#define CHUNK 4096          // edges per partA block
#define NBUCK_MAX 800

// ---------------- y = relu(x @ Wm + bm) -> fp16 ----------------
__global__ __launch_bounds__(256) void k_msg(
    const float* __restrict__ x, const float* __restrict__ W,
    const float* __restrict__ b, __half* __restrict__ y, int n, int nwaves) {
  int tid = threadIdx.x;
  int w = tid >> 6, j = tid & 63;
  float wreg[64];
#pragma unroll
  for (int k = 0; k < 64; ++k) wreg[k] = W[k * 64 + j];
  float bj = b[j];
  __shared__ float xs[4][64];
  for (int i = blockIdx.x * 4 + w; i < n; i += nwaves) {
    xs[w][j] = x[(size_t)i * 64 + j];
    float a0 = bj, a1 = 0.0f, a2 = 0.0f, a3 = 0.0f;
#pragma unroll
    for (int kb = 0; kb < 4; ++kb) {
      float4 v0 = *(const float4*)&xs[w][kb * 16 + 0];
      float4 v1 = *(const float4*)&xs[w][kb * 16 + 4];
      float4 v2 = *(const float4*)&xs[w][kb * 16 + 8];
      float4 v3 = *(const float4*)&xs[w][kb * 16 + 12];
      a0 = fmaf(v0.x, wreg[kb * 16 + 0], a0);
      a0 = fmaf(v0.y, wreg[kb * 16 + 1], a0);
      a0 = fmaf(v0.z, wreg[kb * 16 + 2], a0);
      a0 = fmaf(v0.w, wreg[kb * 16 + 3], a0);
      a1 = fmaf(v1.x, wreg[kb * 16 + 4], a1);
      a1 = fmaf(v1.y, wreg[kb * 16 + 5], a1);
      a1 = fmaf(v1.z, wreg[kb * 16 + 6], a1);
      a1 = fmaf(v1.w, wreg[kb * 16 + 7], a1);
      a2 = fmaf(v2.x, wreg[kb * 16 + 8], a2);
      a2 = fmaf(v2.y, wreg[kb * 16 + 9], a2);
      a2 = fmaf(v2.z, wreg[kb * 16 + 10], a2);
      a2 = fmaf(v2.w, wreg[kb * 16 + 11], a2);
      a3 = fmaf(v3.x, wreg[kb * 16 + 12], a3);
      a3 = fmaf(v3.y, wreg[kb * 16 + 13], a3);
      a3 = fmaf(v3.z, wreg[kb * 16 + 14], a3);
      a3 = fmaf(v3.w, wreg[kb * 16 + 15], a3);
    }
    float acc = (a0 + a1) + (a2 + a3);
    y[(size_t)i * 64 + j] = __float2half(fmaxf(acc, 0.0f));
  }
}

// ---------------- t = x @ Wu[0:64] + bu -> fp16 (no relu) ----------------
__global__ __launch_bounds__(256) void k_updA(
    const float* __restrict__ x, const float* __restrict__ W,
    const float* __restrict__ b, __half* __restrict__ tq, int n, int nwaves) {
  int tid = threadIdx.x;
  int w = tid >> 6, j = tid & 63;
  float wreg[64];
#pragma unroll
  for (int k = 0; k < 64; ++k) wreg[k] = W[k * 64 + j];   // rows 0..63 (x-part)
  float bj = b[j];
  __shared__ float xs[4][64];
  for (int i = blockIdx.x * 4 + w; i < n; i += nwaves) {
    xs[w][j] = x[(size_t)i * 64 + j];
    float a0 = bj, a1 = 0.0f, a2 = 0.0f, a3 = 0.0f;
#pragma unroll
    for (int kb = 0; kb < 4; ++kb) {
      float4 v0 = *(const float4*)&xs[w][kb * 16 + 0];
      float4 v1 = *(const float4*)&xs[w][kb * 16 + 4];
      float4 v2 = *(const float4*)&xs[w][kb * 16 + 8];
      float4 v3 = *(const float4*)&xs[w][kb * 16 + 12];
      a0 = fmaf(v0.x, wreg[kb * 16 + 0], a0);
      a0 = fmaf(v0.y, wreg[kb * 16 + 1], a0);
      a0 = fmaf(v0.z, wreg[kb * 16 + 2], a0);
      a0 = fmaf(v0.w, wreg[kb * 16 + 3], a0);
      a1 = fmaf(v1.x, wreg[kb * 16 + 4], a1);
      a1 = fmaf(v1.y, wreg[kb * 16 + 5], a1);
      a1 = fmaf(v1.z, wreg[kb * 16 + 6], a1);
      a1 = fmaf(v1.w, wreg[kb * 16 + 7], a1);
      a2 = fmaf(v2.x, wreg[kb * 16 + 8], a2);
      a2 = fmaf(v2.y, wreg[kb * 16 + 9], a2);
      a2 = fmaf(v2.z, wreg[kb * 16 + 10], a2);
      a2 = fmaf(v2.w, wreg[kb * 16 + 11], a2);
      a3 = fmaf(v3.x, wreg[kb * 16 + 12], a3);
      a3 = fmaf(v3.y, wreg[kb * 16 + 13], a3);
      a3 = fmaf(v3.z, wreg[kb * 16 + 14], a3);
      a3 = fmaf(v3.w, wreg[kb * 16 + 15], a3);
    }
    float acc = (a0 + a1) + (a2 + a3);
    tq[(size_t)i * 64 + j] = __float2half(acc);
  }
}

// ---------------- partA: bucket-partition edge records ----------------
// rec = w_bits(32) | dloc(7) | src(17)
__global__ __launch_bounds__(256) void k_partA(
    const int* __restrict__ src, const int* __restrict__ dst,
    const float* __restrict__ ew, unsigned long long* __restrict__ recS,
    int* __restrict__ bucketCur, int E, int nbuck) {
  __shared__ int hist[NBUCK_MAX];
  __shared__ int gbase[NBUCK_MAX];
  int t = threadIdx.x;
  int base = blockIdx.x * CHUNK;

  for (int b = t; b < nbuck; b += 256) hist[b] = 0;
  __syncthreads();

  unsigned long long rec[16];
  int bk[16];
#pragma unroll
  for (int i = 0; i < 16; ++i) {
    int e = base + i * 256 + t;
    if (e < E) {
      int d = dst[e];
      int b = d >> LOG_NPB;
      bk[i] = b;
      rec[i] = ((unsigned long long)__float_as_uint(ew[e]) << 32)
             | ((unsigned long long)(d & (NPB - 1)) << 17)
             | (unsigned)src[e];
      atomicAdd(&hist[b], 1);
    } else {
      bk[i] = -1;
    }
  }
  __syncthreads();
  for (int b = t; b < nbuck; b += 256)
    gbase[b] = atomicAdd(&bucketCur[b], hist[b]);
  __syncthreads();
  for (int b = t; b < nbuck; b += 256) hist[b] = 0;  // reuse as local cursor
  __syncthreads();
#pragma unroll
  for (int i = 0; i < 16; ++i) {
    if (bk[i] >= 0) {
      int b = bk[i];
      int lp = gbase[b] + atomicAdd(&hist[b], 1);
      if (lp < CAP) recS[(size_t)b * CAP + lp] = rec[i];
    }
  }
}

// ---------------- gather: block per bucket, LDS fp32 atomic accumulate ----------------
__global__ __launch_bounds__(256) void k_gather(
    const unsigned long long* __restrict__ recS, const int* __restrict__ bucketCur,
    const __half* __restrict__ y, float* __restrict__ agg, int n) {
  __shared__ float lagg[NPB * DIM];   // 32 KB
  __shared__ int lcnt[NPB];
  int b = blockIdx.x;
  int t = threadIdx.x;
  for (int q = t; q < NPB * DIM; q += 256) lagg[q] = 0.0f;
  for (int q = t; q < NPB; q += 256) lcnt[q] = 0;
  __syncthreads();

  int m = bucketCur[b];
  if (m > CAP) m = CAP;
  int lane = t & 63, wid = t >> 6;
  size_t sbase = (size_t)b * CAP;

  int i = wid;
  for (; i + 4 < m; i += 8) {          // 2-deep: waves stride 4, unroll 2
    unsigned long long r0 = recS[sbase + i];
    unsigned long long r1 = recS[sbase + i + 4];
    float v0 = __half2float(y[(size_t)(r0 & 0x1FFFF) * 64 + lane]);
    float v1 = __half2float(y[(size_t)(r1 & 0x1FFFF) * 64 + lane]);
    float w0 = __uint_as_float((unsigned)(r0 >> 32));
    float w1 = __uint_as_float((unsigned)(r1 >> 32));
    int d0 = (int)((r0 >> 17) & (NPB - 1));
    int d1 = (int)((r1 >> 17) & (NPB - 1));
    atomicAdd(&lagg[d0 * 64 + lane], v0 * w0);
    atomicAdd(&lagg[d1 * 64 + lane], v1 * w1);
    if (lane == 0) { atomicAdd(&lcnt[d0], 1); atomicAdd(&lcnt[d1], 1); }
  }
  for (; i < m; i += 4) {
    unsigned long long r = recS[sbase + i];
    float v = __half2float(y[(size_t)(r & 0x1FFFF) * 64 + lane]);
    float w = __uint_as_float((unsigned)(r >> 32));
    int d = (int)((r >> 17) & (NPB - 1));
    atomicAdd(&lagg[d * 64 + lane], v * w);
    if (lane == 0) atomicAdd(&lcnt[d], 1);
  }
  __syncthreads();

  for (int q = t; q < NPB * DIM; q += 256) {
    int node = (b << LOG_NPB) + (q >> 6);
    if (node < n) {
      float c = (float)lcnt[q >> 6];
      agg[(size_t)node * 64 + (q & 63)] = lagg[q] / fmaxf(c, 1.0f);
    }
  }
}

// ---------------- updB: out = l2norm(relu(t + agg @ Wu[64:128])) ----------------
__global__ __launch_bounds__(256) void k_updB(
    const __half* __restrict__ tq, float* io /* agg in, out */,
    const float* __restrict__ W, int n, int nwaves) {
  int tid = threadIdx.x;
  int w = tid >> 6, j = tid & 63;
  float wreg[64];
#pragma unroll
  for (int k = 0; k < 64; ++k) wreg[k] = W[(64 + k) * 64 + j];  // agg-part rows
  __shared__ float xs[4][64];
  for (int i = blockIdx.x * 4 + w; i < n; i += nwaves) {
    xs[w][j] = io[(size_t)i * 64 + j];     // agg row (mean already applied)
    float a0 = __half2float(tq[(size_t)i * 64 + j]);
    float a1 = 0.0f, a2 = 0.0f, a3 = 0.0f;
#pragma unroll
    for (int kb = 0; kb < 4; ++kb) {
      float4 v0 = *(const float4*)&xs[w][kb * 16 + 0];
      float4 v1 = *(const float4*)&xs[w][kb * 16 + 4];
      float4 v2 = *(const float4*)&xs[w][kb * 16 + 8];
      float4 v3 = *(const float4*)&xs[w][kb * 16 + 12];
      a0 = fmaf(v0.x, wreg[kb * 16 + 0], a0);
      a0 = fmaf(v0.y, wreg[kb * 16 + 1], a0);
      a0 = fmaf(v0.z, wreg[kb * 16 + 2], a0);
      a0 = fmaf(v0.w, wreg[kb * 16 + 3], a0);
      a1 = fmaf(v1.x, wreg[kb * 16 + 4], a1);
      a1 = fmaf(v1.y, wreg[kb * 16 + 5], a1);
      a1 = fmaf(v1.z, wreg[kb * 16 + 6], a1);
      a1 = fmaf(v1.w, wreg[kb * 16 + 7], a1);
      a2 = fmaf(v2.x, wreg[kb * 16 + 8], a2);
      a2 = fmaf(v2.y, wreg[kb * 16 + 9], a2);
      a2 = fmaf(v2.z, wreg[kb * 16 + 10], a2);
      a2 = fmaf(v2.w, wreg[kb * 16 + 11], a2);
      a3 = fmaf(v3.x, wreg[kb * 16 + 12], a3);
      a3 = fmaf(v3.y, wreg[kb * 16 + 13], a3);
      a3 = fmaf(v3.z, wreg[kb * 16 + 14], a3);
      a3 = fmaf(v3.w, wreg[kb * 16 + 15], a3);
    }
    float acc = (a0 + a1) + (a2 + a3);
    float h = fmaxf(acc, 0.0f);
    float ss = h * h;
#pragma unroll
    for (int off = 32; off >= 1; off >>= 1) ss += __shfl_xor(ss, off, 64);
    io[(size_t)i * 64 + j] = h / fmaxf(sqrtf(ss), 1e-12f);
  }
}

extern "C" void kernel_launch(void* const* d_in, const int* in_sizes, int n_in,
                              void* d_out, int out_size, void* d_ws, size_t ws_size,
                              hipStream_t stream) {
  const float* x  = (const float*)d_in[0];
  const int*   ei = (const int*)d_in[1];
  const float* ew = (const float*)d_in[2];
  const float* Wm = (const float*)d_in[3];
  const float* bm = (const float*)d_in[4];
  const float* Wu = (const float*)d_in[5];
  const float* bu = (const float*)d_in[6];

  int n = in_sizes[0] / DIM;   // 100000
  int E = in_sizes[2];         // 1200000
  const int* srcIdx = ei;
  const int* dstIdx = ei + E;
  int nbuck = (n + NPB - 1) >> LOG_NPB;   // 782

  // workspace layout (~38.4 MB): y fp16 | t fp16 | recS u64 | bucketCur
  __half* y  = (__half*)d_ws;                                  // n*64
  __half* tq = y + (size_t)n * DIM;                            // n*64
  unsigned long long* recS = (unsigned long long*)(tq + (size_t)n * DIM); // nbuck*CAP
  int* bucketCur = (int*)(recS + (size_t)nbuck * CAP);         // NBUCK_MAX

  hipMemsetAsync(bucketCur, 0, NBUCK_MAX * sizeof(int), stream);

  int nblkA = (E + CHUNK - 1) / CHUNK;    // 293
  k_partA<<<nblkA, 256, 0, stream>>>(srcIdx, dstIdx, ew, recS, bucketCur, E, nbuck);

  const int NB = 2048, NW = NB * 4;
  k_msg<<<NB, 256, 0, stream>>>(x, Wm, bm, y, n, NW);
  k_updA<<<NB, 256, 0, stream>>>(x, Wu, bu, tq, n, NW);
  k_gather<<<nbuck, 256, 0, stream>>>(recS, bucketCur, y, (float*)d_out, n);
  k_updB<<<NB, 256, 0, stream>>>(tq, (float*)d_out, Wu, n, NW);
}

// Round 7
// 280.510 us; speedup vs baseline: 2.5523x; 2.5523x over previous
//
#include <hip/hip_runtime.h>
#include <hip/hip_fp16.h>

// MessagePassingLayer, pull-based with bucketed CSR build (round-4 pipeline)
// + split update GEMM (round-5's one good idea):
//  y = relu(x@Wm+bm) per NODE, fp16;
//  t = x@Wu[0:64]+bu per NODE, fp16 (wreg[64] per thread -- wreg[128] spills);
//  partA: partition edges into 98 dst-buckets (1024 nodes) via LDS histogram
//         + per-(block,bucket) reserved ranges;
//  partB: per bucket, LDS count + scan -> cnt/rowstart, LDS-cursor binning
//         into contiguous sw windows;
//  gather: half-wave per node, MLP-8 pull of y[src]*w (50K waves of TLP --
//          round-6 lesson: block-per-bucket LDS-atomic gather = 3K waves =
//          latency death, 523us);
//  updB: out = l2norm(relu(t + agg@Wu[64:128])), in-place on d_out.

#define DIM 64
#define NPB 1024            // nodes per bucket
#define LOG_NPB 10
#define NBUCK_MAX 128
#define CAP 16384           // staging capacity per bucket (avg fill 12245)
#define CHUNK 4096          // edges per partA block

// ---------------- y = relu(x @ Wm + bm) -> fp16 ----------------
__global__ __launch_bounds__(256) void k_msg(
    const float* __restrict__ x, const float* __restrict__ W,
    const float* __restrict__ b, __half* __restrict__ y, int n, int nwaves) {
  int tid = threadIdx.x;
  int w = tid >> 6, j = tid & 63;
  float wreg[64];
#pragma unroll
  for (int k = 0; k < 64; ++k) wreg[k] = W[k * 64 + j];
  float bj = b[j];
  __shared__ float xs[4][64];
  for (int i = blockIdx.x * 4 + w; i < n; i += nwaves) {
    xs[w][j] = x[(size_t)i * 64 + j];
    float a0 = bj, a1 = 0.0f, a2 = 0.0f, a3 = 0.0f;
#pragma unroll
    for (int kb = 0; kb < 4; ++kb) {
      float4 v0 = *(const float4*)&xs[w][kb * 16 + 0];
      float4 v1 = *(const float4*)&xs[w][kb * 16 + 4];
      float4 v2 = *(const float4*)&xs[w][kb * 16 + 8];
      float4 v3 = *(const float4*)&xs[w][kb * 16 + 12];
      a0 = fmaf(v0.x, wreg[kb * 16 + 0], a0);
      a0 = fmaf(v0.y, wreg[kb * 16 + 1], a0);
      a0 = fmaf(v0.z, wreg[kb * 16 + 2], a0);
      a0 = fmaf(v0.w, wreg[kb * 16 + 3], a0);
      a1 = fmaf(v1.x, wreg[kb * 16 + 4], a1);
      a1 = fmaf(v1.y, wreg[kb * 16 + 5], a1);
      a1 = fmaf(v1.z, wreg[kb * 16 + 6], a1);
      a1 = fmaf(v1.w, wreg[kb * 16 + 7], a1);
      a2 = fmaf(v2.x, wreg[kb * 16 + 8], a2);
      a2 = fmaf(v2.y, wreg[kb * 16 + 9], a2);
      a2 = fmaf(v2.z, wreg[kb * 16 + 10], a2);
      a2 = fmaf(v2.w, wreg[kb * 16 + 11], a2);
      a3 = fmaf(v3.x, wreg[kb * 16 + 12], a3);
      a3 = fmaf(v3.y, wreg[kb * 16 + 13], a3);
      a3 = fmaf(v3.z, wreg[kb * 16 + 14], a3);
      a3 = fmaf(v3.w, wreg[kb * 16 + 15], a3);
    }
    float acc = (a0 + a1) + (a2 + a3);
    y[(size_t)i * 64 + j] = __float2half(fmaxf(acc, 0.0f));
  }
}

// ---------------- t = x @ Wu[0:64] + bu -> fp16 (no relu) ----------------
__global__ __launch_bounds__(256) void k_updA(
    const float* __restrict__ x, const float* __restrict__ W,
    const float* __restrict__ b, __half* __restrict__ tq, int n, int nwaves) {
  int tid = threadIdx.x;
  int w = tid >> 6, j = tid & 63;
  float wreg[64];
#pragma unroll
  for (int k = 0; k < 64; ++k) wreg[k] = W[k * 64 + j];   // rows 0..63 (x-part)
  float bj = b[j];
  __shared__ float xs[4][64];
  for (int i = blockIdx.x * 4 + w; i < n; i += nwaves) {
    xs[w][j] = x[(size_t)i * 64 + j];
    float a0 = bj, a1 = 0.0f, a2 = 0.0f, a3 = 0.0f;
#pragma unroll
    for (int kb = 0; kb < 4; ++kb) {
      float4 v0 = *(const float4*)&xs[w][kb * 16 + 0];
      float4 v1 = *(const float4*)&xs[w][kb * 16 + 4];
      float4 v2 = *(const float4*)&xs[w][kb * 16 + 8];
      float4 v3 = *(const float4*)&xs[w][kb * 16 + 12];
      a0 = fmaf(v0.x, wreg[kb * 16 + 0], a0);
      a0 = fmaf(v0.y, wreg[kb * 16 + 1], a0);
      a0 = fmaf(v0.z, wreg[kb * 16 + 2], a0);
      a0 = fmaf(v0.w, wreg[kb * 16 + 3], a0);
      a1 = fmaf(v1.x, wreg[kb * 16 + 4], a1);
      a1 = fmaf(v1.y, wreg[kb * 16 + 5], a1);
      a1 = fmaf(v1.z, wreg[kb * 16 + 6], a1);
      a1 = fmaf(v1.w, wreg[kb * 16 + 7], a1);
      a2 = fmaf(v2.x, wreg[kb * 16 + 8], a2);
      a2 = fmaf(v2.y, wreg[kb * 16 + 9], a2);
      a2 = fmaf(v2.z, wreg[kb * 16 + 10], a2);
      a2 = fmaf(v2.w, wreg[kb * 16 + 11], a2);
      a3 = fmaf(v3.x, wreg[kb * 16 + 12], a3);
      a3 = fmaf(v3.y, wreg[kb * 16 + 13], a3);
      a3 = fmaf(v3.z, wreg[kb * 16 + 14], a3);
      a3 = fmaf(v3.w, wreg[kb * 16 + 15], a3);
    }
    float acc = (a0 + a1) + (a2 + a3);
    tq[(size_t)i * 64 + j] = __float2half(acc);
  }
}

// ---------------- partA: bucket-partition edges ----------------
__global__ __launch_bounds__(256) void k_partA(
    const int* __restrict__ src, const int* __restrict__ dst,
    const float* __restrict__ ew,
    unsigned long long* __restrict__ recS, unsigned short* __restrict__ dlocS,
    int* __restrict__ bucketCur, int E, int nbuck) {
  __shared__ int hist[NBUCK_MAX];
  __shared__ int gbase[NBUCK_MAX];
  int t = threadIdx.x;
  int base = blockIdx.x * CHUNK;

  for (int b = t; b < nbuck; b += 256) hist[b] = 0;
  __syncthreads();

  unsigned long long rec[16];
  unsigned short dl[16];
  short bk[16];
#pragma unroll
  for (int i = 0; i < 16; ++i) {
    int e = base + i * 256 + t;
    if (e < E) {
      int d = dst[e];
      int b = d >> LOG_NPB;
      bk[i] = (short)b;
      dl[i] = (unsigned short)(d & (NPB - 1));
      rec[i] = ((unsigned long long)__float_as_uint(ew[e]) << 32) | (unsigned)src[e];
      atomicAdd(&hist[b], 1);
    } else {
      bk[i] = -1;
    }
  }
  __syncthreads();
  for (int b = t; b < nbuck; b += 256)
    gbase[b] = atomicAdd(&bucketCur[b], hist[b]);
  __syncthreads();
  for (int b = t; b < nbuck; b += 256) hist[b] = 0;  // reuse as local cursor
  __syncthreads();
#pragma unroll
  for (int i = 0; i < 16; ++i) {
    if (bk[i] >= 0) {
      int b = bk[i];
      int lp = gbase[b] + atomicAdd(&hist[b], 1);
      if (lp < CAP) {                    // paranoia clamp (never hit for uniform dst)
        int pos = b * CAP + lp;
        recS[pos] = rec[i];
        dlocS[pos] = dl[i];
      }
    }
  }
}

// ---------------- exclusive scan of bucket totals (nbuck <= 128) ----------------
__global__ __launch_bounds__(128) void k_scanBk(const int* __restrict__ bucketCur,
                                                int* __restrict__ btotscan, int nbuck) {
  int tid = threadIdx.x, lane = tid & 63;
  int v = tid < nbuck ? bucketCur[tid] : 0;
  int incl = v;
#pragma unroll
  for (int off = 1; off < 64; off <<= 1) {
    int tt = __shfl_up(incl, off, 64);
    if (lane >= off) incl += tt;
  }
  __shared__ int wt[2];
  if (lane == 63) wt[tid >> 6] = incl;
  __syncthreads();
  int add = (tid >= 64) ? wt[0] : 0;
  if (tid < nbuck) btotscan[tid] = incl - v + add;
}

// ---------------- partB: per-bucket count + scan + bin ----------------
__global__ __launch_bounds__(256) void k_partB(
    const unsigned long long* __restrict__ recS, const unsigned short* __restrict__ dlocS,
    const int* __restrict__ bucketCur, const int* __restrict__ btotscan,
    unsigned long long* __restrict__ sw, int* __restrict__ cnt,
    int* __restrict__ rowstart, int n) {
  __shared__ int lcnt[NPB];
  __shared__ int loff[NPB];
  __shared__ int wsum[4];
  int b = blockIdx.x;
  int t = threadIdx.x;
  int m = bucketCur[b];
  if (m > CAP) m = CAP;
  int sbase = b * CAP;
  int bktbase = btotscan[b];

  for (int i = t; i < NPB; i += 256) lcnt[i] = 0;
  __syncthreads();
  for (int i = t; i < m; i += 256)
    atomicAdd(&lcnt[dlocS[sbase + i]], 1);
  __syncthreads();

  // exclusive scan of lcnt[0..1023], 4 entries/thread
  int v[4];
#pragma unroll
  for (int k = 0; k < 4; ++k) v[k] = lcnt[t * 4 + k];
  int s = v[0] + v[1] + v[2] + v[3];
  int lane = t & 63;
  int incl = s;
#pragma unroll
  for (int off = 1; off < 64; off <<= 1) {
    int tt = __shfl_up(incl, off, 64);
    if (lane >= off) incl += tt;
  }
  if (lane == 63) wsum[t >> 6] = incl;
  __syncthreads();
  int woff = 0;
  for (int w = 0; w < (t >> 6); ++w) woff += wsum[w];
  int ebase = incl - s + woff;
  int pre = ebase;
#pragma unroll
  for (int k = 0; k < 4; ++k) {
    loff[t * 4 + k] = pre;
    int gn = (b << LOG_NPB) + t * 4 + k;
    if (gn < n) {
      cnt[gn] = v[k];
      rowstart[gn] = bktbase + pre;
    }
    pre += v[k];
  }
  __syncthreads();

  // bin records via LDS cursors; writes stay in bucket's contiguous sw window
  for (int i = t; i < m; i += 256) {
    int dl = dlocS[sbase + i];
    int p = atomicAdd(&loff[dl], 1);
    sw[bktbase + p] = recS[sbase + i];
  }
}

// ---------------- pull-gather: half-wave per node, MLP-8, fp16 y ----------------
__global__ __launch_bounds__(256) void k_gather(
    const unsigned long long* __restrict__ sw, const int* __restrict__ rowstart,
    const int* __restrict__ cnt, const __half2* __restrict__ y2,
    float* __restrict__ agg, int n) {
  int lane = threadIdx.x & 31;
  int node = (int)((blockIdx.x * (size_t)blockDim.x + threadIdx.x) >> 5);
  if (node >= n) return;
  int c = cnt[node];
  int e = rowstart[node];
  int end = e + c;
  float ax = 0.0f, ay = 0.0f;
  for (; e + 8 <= end; e += 8) {
    unsigned long long r0 = sw[e + 0];
    unsigned long long r1 = sw[e + 1];
    unsigned long long r2 = sw[e + 2];
    unsigned long long r3 = sw[e + 3];
    unsigned long long r4 = sw[e + 4];
    unsigned long long r5 = sw[e + 5];
    unsigned long long r6 = sw[e + 6];
    unsigned long long r7 = sw[e + 7];
    __half2 v0 = y2[(size_t)(unsigned)r0 * 32 + lane];
    __half2 v1 = y2[(size_t)(unsigned)r1 * 32 + lane];
    __half2 v2 = y2[(size_t)(unsigned)r2 * 32 + lane];
    __half2 v3 = y2[(size_t)(unsigned)r3 * 32 + lane];
    __half2 v4 = y2[(size_t)(unsigned)r4 * 32 + lane];
    __half2 v5 = y2[(size_t)(unsigned)r5 * 32 + lane];
    __half2 v6 = y2[(size_t)(unsigned)r6 * 32 + lane];
    __half2 v7 = y2[(size_t)(unsigned)r7 * 32 + lane];
    float w0 = __uint_as_float((unsigned)(r0 >> 32));
    float w1 = __uint_as_float((unsigned)(r1 >> 32));
    float w2 = __uint_as_float((unsigned)(r2 >> 32));
    float w3 = __uint_as_float((unsigned)(r3 >> 32));
    float w4 = __uint_as_float((unsigned)(r4 >> 32));
    float w5 = __uint_as_float((unsigned)(r5 >> 32));
    float w6 = __uint_as_float((unsigned)(r6 >> 32));
    float w7 = __uint_as_float((unsigned)(r7 >> 32));
    float2 f0 = __half22float2(v0);
    float2 f1 = __half22float2(v1);
    float2 f2 = __half22float2(v2);
    float2 f3 = __half22float2(v3);
    float2 f4 = __half22float2(v4);
    float2 f5 = __half22float2(v5);
    float2 f6 = __half22float2(v6);
    float2 f7 = __half22float2(v7);
    ax = fmaf(f0.x, w0, ax); ay = fmaf(f0.y, w0, ay);
    ax = fmaf(f1.x, w1, ax); ay = fmaf(f1.y, w1, ay);
    ax = fmaf(f2.x, w2, ax); ay = fmaf(f2.y, w2, ay);
    ax = fmaf(f3.x, w3, ax); ay = fmaf(f3.y, w3, ay);
    ax = fmaf(f4.x, w4, ax); ay = fmaf(f4.y, w4, ay);
    ax = fmaf(f5.x, w5, ax); ay = fmaf(f5.y, w5, ay);
    ax = fmaf(f6.x, w6, ax); ay = fmaf(f6.y, w6, ay);
    ax = fmaf(f7.x, w7, ax); ay = fmaf(f7.y, w7, ay);
  }
  for (; e + 4 <= end; e += 4) {
    unsigned long long r0 = sw[e + 0];
    unsigned long long r1 = sw[e + 1];
    unsigned long long r2 = sw[e + 2];
    unsigned long long r3 = sw[e + 3];
    __half2 v0 = y2[(size_t)(unsigned)r0 * 32 + lane];
    __half2 v1 = y2[(size_t)(unsigned)r1 * 32 + lane];
    __half2 v2 = y2[(size_t)(unsigned)r2 * 32 + lane];
    __half2 v3 = y2[(size_t)(unsigned)r3 * 32 + lane];
    float w0 = __uint_as_float((unsigned)(r0 >> 32));
    float w1 = __uint_as_float((unsigned)(r1 >> 32));
    float w2 = __uint_as_float((unsigned)(r2 >> 32));
    float w3 = __uint_as_float((unsigned)(r3 >> 32));
    float2 f0 = __half22float2(v0);
    float2 f1 = __half22float2(v1);
    float2 f2 = __half22float2(v2);
    float2 f3 = __half22float2(v3);
    ax = fmaf(f0.x, w0, ax); ay = fmaf(f0.y, w0, ay);
    ax = fmaf(f1.x, w1, ax); ay = fmaf(f1.y, w1, ay);
    ax = fmaf(f2.x, w2, ax); ay = fmaf(f2.y, w2, ay);
    ax = fmaf(f3.x, w3, ax); ay = fmaf(f3.y, w3, ay);
  }
  for (; e < end; ++e) {
    unsigned long long r = sw[e];
    __half2 vv = y2[(size_t)(unsigned)r * 32 + lane];
    float w = __uint_as_float((unsigned)(r >> 32));
    float2 f = __half22float2(vv);
    ax = fmaf(f.x, w, ax); ay = fmaf(f.y, w, ay);
  }
  float invd = 1.0f / fmaxf((float)c, 1.0f);
  float2 o; o.x = ax * invd; o.y = ay * invd;
  *(float2*)&agg[(size_t)node * 64 + lane * 2] = o;
}

// ---------------- updB: out = l2norm(relu(t + agg @ Wu[64:128])) ----------------
__global__ __launch_bounds__(256) void k_updB(
    const __half* __restrict__ tq, float* io /* agg in, out */,
    const float* __restrict__ W, int n, int nwaves) {
  int tid = threadIdx.x;
  int w = tid >> 6, j = tid & 63;
  float wreg[64];
#pragma unroll
  for (int k = 0; k < 64; ++k) wreg[k] = W[(64 + k) * 64 + j];  // agg-part rows
  __shared__ float xs[4][64];
  for (int i = blockIdx.x * 4 + w; i < n; i += nwaves) {
    xs[w][j] = io[(size_t)i * 64 + j];     // agg row (mean already applied)
    float a0 = __half2float(tq[(size_t)i * 64 + j]);
    float a1 = 0.0f, a2 = 0.0f, a3 = 0.0f;
#pragma unroll
    for (int kb = 0; kb < 4; ++kb) {
      float4 v0 = *(const float4*)&xs[w][kb * 16 + 0];
      float4 v1 = *(const float4*)&xs[w][kb * 16 + 4];
      float4 v2 = *(const float4*)&xs[w][kb * 16 + 8];
      float4 v3 = *(const float4*)&xs[w][kb * 16 + 12];
      a0 = fmaf(v0.x, wreg[kb * 16 + 0], a0);
      a0 = fmaf(v0.y, wreg[kb * 16 + 1], a0);
      a0 = fmaf(v0.z, wreg[kb * 16 + 2], a0);
      a0 = fmaf(v0.w, wreg[kb * 16 + 3], a0);
      a1 = fmaf(v1.x, wreg[kb * 16 + 4], a1);
      a1 = fmaf(v1.y, wreg[kb * 16 + 5], a1);
      a1 = fmaf(v1.z, wreg[kb * 16 + 6], a1);
      a1 = fmaf(v1.w, wreg[kb * 16 + 7], a1);
      a2 = fmaf(v2.x, wreg[kb * 16 + 8], a2);
      a2 = fmaf(v2.y, wreg[kb * 16 + 9], a2);
      a2 = fmaf(v2.z, wreg[kb * 16 + 10], a2);
      a2 = fmaf(v2.w, wreg[kb * 16 + 11], a2);
      a3 = fmaf(v3.x, wreg[kb * 16 + 12], a3);
      a3 = fmaf(v3.y, wreg[kb * 16 + 13], a3);
      a3 = fmaf(v3.z, wreg[kb * 16 + 14], a3);
      a3 = fmaf(v3.w, wreg[kb * 16 + 15], a3);
    }
    float acc = (a0 + a1) + (a2 + a3);
    float h = fmaxf(acc, 0.0f);
    float ss = h * h;
#pragma unroll
    for (int off = 32; off >= 1; off >>= 1) ss += __shfl_xor(ss, off, 64);
    io[(size_t)i * 64 + j] = h / fmaxf(sqrtf(ss), 1e-12f);
  }
}

extern "C" void kernel_launch(void* const* d_in, const int* in_sizes, int n_in,
                              void* d_out, int out_size, void* d_ws, size_t ws_size,
                              hipStream_t stream) {
  const float* x  = (const float*)d_in[0];
  const int*   ei = (const int*)d_in[1];
  const float* ew = (const float*)d_in[2];
  const float* Wm = (const float*)d_in[3];
  const float* bm = (const float*)d_in[4];
  const float* Wu = (const float*)d_in[5];
  const float* bu = (const float*)d_in[6];

  int n = in_sizes[0] / DIM;   // 100000
  int E = in_sizes[2];         // 1200000
  const int* srcIdx = ei;
  const int* dstIdx = ei + E;
  int nbuck = (n + NPB - 1) >> LOG_NPB;   // 98

  // workspace layout (~41 MB): y | t | sw | recS | dlocS | cnt | rowstart | ...
  __half* y  = (__half*)d_ws;                                           // n*64 fp16
  __half* tq = y + (size_t)n * DIM;                                     // n*64 fp16
  unsigned long long* sw = (unsigned long long*)(tq + (size_t)n * DIM); // E u64
  unsigned long long* recS = sw + E;                                    // nbuck*CAP u64
  unsigned short* dlocS = (unsigned short*)(recS + (size_t)nbuck * CAP);// nbuck*CAP u16
  int* cnt      = (int*)(dlocS + (size_t)nbuck * CAP);                  // n
  int* rowstart = cnt + n;                                              // n
  int* bucketCur = rowstart + n;                                        // NBUCK_MAX
  int* btotscan  = bucketCur + NBUCK_MAX;                               // NBUCK_MAX

  hipMemsetAsync(bucketCur, 0, NBUCK_MAX * sizeof(int), stream);

  int nblkA = (E + CHUNK - 1) / CHUNK;    // 293
  k_partA<<<nblkA, 256, 0, stream>>>(srcIdx, dstIdx, ew, recS, dlocS, bucketCur, E, nbuck);
  k_scanBk<<<1, 128, 0, stream>>>(bucketCur, btotscan, nbuck);
  k_partB<<<nbuck, 256, 0, stream>>>(recS, dlocS, bucketCur, btotscan, sw, cnt, rowstart, n);

  const int NB = 2048, NW = NB * 4;
  k_msg<<<NB, 256, 0, stream>>>(x, Wm, bm, y, n, NW);
  k_updA<<<NB, 256, 0, stream>>>(x, Wu, bu, tq, n, NW);
  k_gather<<<(n + 7) / 8, 256, 0, stream>>>(sw, rowstart, cnt, (const __half2*)y,
                                            (float*)d_out, n);
  k_updB<<<NB, 256, 0, stream>>>(tq, (float*)d_out, Wu, n, NW);
}

// Round 8
// 269.640 us; speedup vs baseline: 2.6552x; 1.0403x over previous
//
#include <hip/hip_runtime.h>
#include <hip/hip_fp16.h>

// MessagePassingLayer, pull-based, 256-node-bucket CSR build:
//  y = relu(x@Wm+bm) per NODE, fp16;
//  t = x@Wu[0:64]+bu per NODE, fp16 (aliases recS; wreg[128] spills, 64 ok);
//  partA: partition edges into 391 dst-buckets (256 nodes) via LDS histogram
//         + per-(block,bucket) reserved ranges (586 blocks; r7 lesson:
//         98-block partB = 3% occupancy = latency death);
//  partB: per bucket (391 blocks), LDS count + 1-entry/thread scan ->
//         cnt/rowstart, LDS-cursor binning into contiguous sw windows;
//  gupd:  FUSED gather+update: half-wave per node pulls mean(y[src]*w) ->
//         2KB LDS -> same block does agg-half GEMM + l2norm -> d_out.
//         Saves the 51MB agg HBM round-trip of a separate updB.

#define DIM 64
#define NPB 256             // nodes per bucket
#define LOG_NPB 8
#define NBUCK_MAX 512
#define CAP 4096            // records per bucket (mean 3072, sigma ~55)
#define CHUNK 2048          // edges per partA block
#define EPT 8               // edges per thread in partA

// ---------------- y = relu(x @ Wm + bm) -> fp16 ----------------
__global__ __launch_bounds__(256) void k_msg(
    const float* __restrict__ x, const float* __restrict__ W,
    const float* __restrict__ b, __half* __restrict__ y, int n, int nwaves) {
  int tid = threadIdx.x;
  int w = tid >> 6, j = tid & 63;
  float wreg[64];
#pragma unroll
  for (int k = 0; k < 64; ++k) wreg[k] = W[k * 64 + j];
  float bj = b[j];
  __shared__ float xs[4][64];
  for (int i = blockIdx.x * 4 + w; i < n; i += nwaves) {
    xs[w][j] = x[(size_t)i * 64 + j];
    float a0 = bj, a1 = 0.0f, a2 = 0.0f, a3 = 0.0f;
#pragma unroll
    for (int kb = 0; kb < 4; ++kb) {
      float4 v0 = *(const float4*)&xs[w][kb * 16 + 0];
      float4 v1 = *(const float4*)&xs[w][kb * 16 + 4];
      float4 v2 = *(const float4*)&xs[w][kb * 16 + 8];
      float4 v3 = *(const float4*)&xs[w][kb * 16 + 12];
      a0 = fmaf(v0.x, wreg[kb * 16 + 0], a0);
      a0 = fmaf(v0.y, wreg[kb * 16 + 1], a0);
      a0 = fmaf(v0.z, wreg[kb * 16 + 2], a0);
      a0 = fmaf(v0.w, wreg[kb * 16 + 3], a0);
      a1 = fmaf(v1.x, wreg[kb * 16 + 4], a1);
      a1 = fmaf(v1.y, wreg[kb * 16 + 5], a1);
      a1 = fmaf(v1.z, wreg[kb * 16 + 6], a1);
      a1 = fmaf(v1.w, wreg[kb * 16 + 7], a1);
      a2 = fmaf(v2.x, wreg[kb * 16 + 8], a2);
      a2 = fmaf(v2.y, wreg[kb * 16 + 9], a2);
      a2 = fmaf(v2.z, wreg[kb * 16 + 10], a2);
      a2 = fmaf(v2.w, wreg[kb * 16 + 11], a2);
      a3 = fmaf(v3.x, wreg[kb * 16 + 12], a3);
      a3 = fmaf(v3.y, wreg[kb * 16 + 13], a3);
      a3 = fmaf(v3.z, wreg[kb * 16 + 14], a3);
      a3 = fmaf(v3.w, wreg[kb * 16 + 15], a3);
    }
    float acc = (a0 + a1) + (a2 + a3);
    y[(size_t)i * 64 + j] = __float2half(fmaxf(acc, 0.0f));
  }
}

// ---------------- t = x @ Wu[0:64] + bu -> fp16 (no relu) ----------------
__global__ __launch_bounds__(256) void k_updA(
    const float* __restrict__ x, const float* __restrict__ W,
    const float* __restrict__ b, __half* __restrict__ tq, int n, int nwaves) {
  int tid = threadIdx.x;
  int w = tid >> 6, j = tid & 63;
  float wreg[64];
#pragma unroll
  for (int k = 0; k < 64; ++k) wreg[k] = W[k * 64 + j];   // rows 0..63 (x-part)
  float bj = b[j];
  __shared__ float xs[4][64];
  for (int i = blockIdx.x * 4 + w; i < n; i += nwaves) {
    xs[w][j] = x[(size_t)i * 64 + j];
    float a0 = bj, a1 = 0.0f, a2 = 0.0f, a3 = 0.0f;
#pragma unroll
    for (int kb = 0; kb < 4; ++kb) {
      float4 v0 = *(const float4*)&xs[w][kb * 16 + 0];
      float4 v1 = *(const float4*)&xs[w][kb * 16 + 4];
      float4 v2 = *(const float4*)&xs[w][kb * 16 + 8];
      float4 v3 = *(const float4*)&xs[w][kb * 16 + 12];
      a0 = fmaf(v0.x, wreg[kb * 16 + 0], a0);
      a0 = fmaf(v0.y, wreg[kb * 16 + 1], a0);
      a0 = fmaf(v0.z, wreg[kb * 16 + 2], a0);
      a0 = fmaf(v0.w, wreg[kb * 16 + 3], a0);
      a1 = fmaf(v1.x, wreg[kb * 16 + 4], a1);
      a1 = fmaf(v1.y, wreg[kb * 16 + 5], a1);
      a1 = fmaf(v1.z, wreg[kb * 16 + 6], a1);
      a1 = fmaf(v1.w, wreg[kb * 16 + 7], a1);
      a2 = fmaf(v2.x, wreg[kb * 16 + 8], a2);
      a2 = fmaf(v2.y, wreg[kb * 16 + 9], a2);
      a2 = fmaf(v2.z, wreg[kb * 16 + 10], a2);
      a2 = fmaf(v2.w, wreg[kb * 16 + 11], a2);
      a3 = fmaf(v3.x, wreg[kb * 16 + 12], a3);
      a3 = fmaf(v3.y, wreg[kb * 16 + 13], a3);
      a3 = fmaf(v3.z, wreg[kb * 16 + 14], a3);
      a3 = fmaf(v3.w, wreg[kb * 16 + 15], a3);
    }
    float acc = (a0 + a1) + (a2 + a3);
    tq[(size_t)i * 64 + j] = __float2half(acc);
  }
}

// ---------------- partA: bucket-partition edges ----------------
__global__ __launch_bounds__(256) void k_partA(
    const int* __restrict__ src, const int* __restrict__ dst,
    const float* __restrict__ ew,
    unsigned long long* __restrict__ recS, unsigned char* __restrict__ dlocS,
    int* __restrict__ bucketCur, int E, int nbuck) {
  __shared__ int hist[NBUCK_MAX];
  __shared__ int gbase[NBUCK_MAX];
  int t = threadIdx.x;
  int base = blockIdx.x * CHUNK;

  for (int b = t; b < nbuck; b += 256) hist[b] = 0;
  __syncthreads();

  unsigned long long rec[EPT];
  unsigned char dl[EPT];
  short bk[EPT];
#pragma unroll
  for (int i = 0; i < EPT; ++i) {
    int e = base + i * 256 + t;
    if (e < E) {
      int d = dst[e];
      int b = d >> LOG_NPB;
      bk[i] = (short)b;
      dl[i] = (unsigned char)(d & (NPB - 1));
      rec[i] = ((unsigned long long)__float_as_uint(ew[e]) << 32) | (unsigned)src[e];
      atomicAdd(&hist[b], 1);
    } else {
      bk[i] = -1;
    }
  }
  __syncthreads();
  for (int b = t; b < nbuck; b += 256)
    gbase[b] = atomicAdd(&bucketCur[b], hist[b]);
  __syncthreads();
  for (int b = t; b < nbuck; b += 256) hist[b] = 0;  // reuse as local cursor
  __syncthreads();
#pragma unroll
  for (int i = 0; i < EPT; ++i) {
    if (bk[i] >= 0) {
      int b = bk[i];
      int lp = gbase[b] + atomicAdd(&hist[b], 1);
      if (lp < CAP) {                    // paranoia clamp (never hit, 18 sigma)
        size_t pos = (size_t)b * CAP + lp;
        recS[pos] = rec[i];
        dlocS[pos] = dl[i];
      }
    }
  }
}

// ---------------- exclusive scan of bucket totals (nbuck <= 512) ----------------
__global__ __launch_bounds__(512) void k_scanBk(const int* __restrict__ bucketCur,
                                                int* __restrict__ btotscan, int nbuck) {
  int tid = threadIdx.x, lane = tid & 63, wv = tid >> 6;
  int v = tid < nbuck ? bucketCur[tid] : 0;
  int incl = v;
#pragma unroll
  for (int off = 1; off < 64; off <<= 1) {
    int tt = __shfl_up(incl, off, 64);
    if (lane >= off) incl += tt;
  }
  __shared__ int wt[8];
  if (lane == 63) wt[wv] = incl;
  __syncthreads();
  int add = 0;
  for (int q = 0; q < wv; ++q) add += wt[q];
  if (tid < nbuck) btotscan[tid] = incl - v + add;
}

// ---------------- partB: per-bucket count + scan + bin (391 blocks) ----------------
__global__ __launch_bounds__(256) void k_partB(
    const unsigned long long* __restrict__ recS, const unsigned char* __restrict__ dlocS,
    const int* __restrict__ bucketCur, const int* __restrict__ btotscan,
    unsigned long long* __restrict__ sw, int* __restrict__ cnt,
    int* __restrict__ rowstart, int n) {
  __shared__ int lcnt[NPB];
  __shared__ int loff[NPB];
  __shared__ int wsum[4];
  int b = blockIdx.x;
  int t = threadIdx.x;
  int m = bucketCur[b];
  if (m > CAP) m = CAP;
  size_t sbase = (size_t)b * CAP;
  int bktbase = btotscan[b];

  lcnt[t] = 0;
  __syncthreads();
  for (int i = t; i < m; i += 256)
    atomicAdd(&lcnt[dlocS[sbase + i]], 1);
  __syncthreads();

  // exclusive scan of lcnt[0..255], 1 entry/thread
  int v = lcnt[t];
  int lane = t & 63;
  int incl = v;
#pragma unroll
  for (int off = 1; off < 64; off <<= 1) {
    int tt = __shfl_up(incl, off, 64);
    if (lane >= off) incl += tt;
  }
  if (lane == 63) wsum[t >> 6] = incl;
  __syncthreads();
  int woff = 0;
  for (int q = 0; q < (t >> 6); ++q) woff += wsum[q];
  int excl = incl - v + woff;
  loff[t] = excl;
  int gn = (b << LOG_NPB) + t;
  if (gn < n) {
    cnt[gn] = v;
    rowstart[gn] = bktbase + excl;
  }
  __syncthreads();

  // bin records via LDS cursors; writes stay in bucket's contiguous sw window
  for (int i = t; i < m; i += 256) {
    int dl = dlocS[sbase + i];
    int p = atomicAdd(&loff[dl], 1);
    sw[bktbase + p] = recS[sbase + i];
  }
}

// ---------------- fused gather + updB ----------------
// half-wave per node: agg = mean(y[src]*w) -> LDS; then block GEMMs the
// agg-half of Wu, adds t, relu, l2norm, writes d_out.
__global__ __launch_bounds__(256) void k_gupd(
    const unsigned long long* __restrict__ sw, const int* __restrict__ rowstart,
    const int* __restrict__ cnt, const __half2* __restrict__ y2,
    const __half* __restrict__ tq, const float* __restrict__ W,
    float* __restrict__ out, int n) {
  float wreg[64];
  int j = threadIdx.x & 63;
#pragma unroll
  for (int k = 0; k < 64; ++k) wreg[k] = W[(64 + k) * 64 + j];  // agg-part rows
  __shared__ float aggs[8][64];
  int lane = threadIdx.x & 31, hw = threadIdx.x >> 5;
  int ngroups = (n + 7) >> 3;

  for (int g = blockIdx.x; g < ngroups; g += gridDim.x) {
    int node = g * 8 + hw;
    float ax = 0.0f, ay = 0.0f, invc = 0.0f;
    if (node < n) {
      int c = cnt[node];
      int e = rowstart[node];
      int end = e + c;
      for (; e + 8 <= end; e += 8) {
        unsigned long long r0 = sw[e + 0];
        unsigned long long r1 = sw[e + 1];
        unsigned long long r2 = sw[e + 2];
        unsigned long long r3 = sw[e + 3];
        unsigned long long r4 = sw[e + 4];
        unsigned long long r5 = sw[e + 5];
        unsigned long long r6 = sw[e + 6];
        unsigned long long r7 = sw[e + 7];
        __half2 v0 = y2[(size_t)(unsigned)r0 * 32 + lane];
        __half2 v1 = y2[(size_t)(unsigned)r1 * 32 + lane];
        __half2 v2 = y2[(size_t)(unsigned)r2 * 32 + lane];
        __half2 v3 = y2[(size_t)(unsigned)r3 * 32 + lane];
        __half2 v4 = y2[(size_t)(unsigned)r4 * 32 + lane];
        __half2 v5 = y2[(size_t)(unsigned)r5 * 32 + lane];
        __half2 v6 = y2[(size_t)(unsigned)r6 * 32 + lane];
        __half2 v7 = y2[(size_t)(unsigned)r7 * 32 + lane];
        float w0 = __uint_as_float((unsigned)(r0 >> 32));
        float w1 = __uint_as_float((unsigned)(r1 >> 32));
        float w2 = __uint_as_float((unsigned)(r2 >> 32));
        float w3 = __uint_as_float((unsigned)(r3 >> 32));
        float w4 = __uint_as_float((unsigned)(r4 >> 32));
        float w5 = __uint_as_float((unsigned)(r5 >> 32));
        float w6 = __uint_as_float((unsigned)(r6 >> 32));
        float w7 = __uint_as_float((unsigned)(r7 >> 32));
        float2 f0 = __half22float2(v0);
        float2 f1 = __half22float2(v1);
        float2 f2 = __half22float2(v2);
        float2 f3 = __half22float2(v3);
        float2 f4 = __half22float2(v4);
        float2 f5 = __half22float2(v5);
        float2 f6 = __half22float2(v6);
        float2 f7 = __half22float2(v7);
        ax = fmaf(f0.x, w0, ax); ay = fmaf(f0.y, w0, ay);
        ax = fmaf(f1.x, w1, ax); ay = fmaf(f1.y, w1, ay);
        ax = fmaf(f2.x, w2, ax); ay = fmaf(f2.y, w2, ay);
        ax = fmaf(f3.x, w3, ax); ay = fmaf(f3.y, w3, ay);
        ax = fmaf(f4.x, w4, ax); ay = fmaf(f4.y, w4, ay);
        ax = fmaf(f5.x, w5, ax); ay = fmaf(f5.y, w5, ay);
        ax = fmaf(f6.x, w6, ax); ay = fmaf(f6.y, w6, ay);
        ax = fmaf(f7.x, w7, ax); ay = fmaf(f7.y, w7, ay);
      }
      for (; e + 4 <= end; e += 4) {
        unsigned long long r0 = sw[e + 0];
        unsigned long long r1 = sw[e + 1];
        unsigned long long r2 = sw[e + 2];
        unsigned long long r3 = sw[e + 3];
        __half2 v0 = y2[(size_t)(unsigned)r0 * 32 + lane];
        __half2 v1 = y2[(size_t)(unsigned)r1 * 32 + lane];
        __half2 v2 = y2[(size_t)(unsigned)r2 * 32 + lane];
        __half2 v3 = y2[(size_t)(unsigned)r3 * 32 + lane];
        float w0 = __uint_as_float((unsigned)(r0 >> 32));
        float w1 = __uint_as_float((unsigned)(r1 >> 32));
        float w2 = __uint_as_float((unsigned)(r2 >> 32));
        float w3 = __uint_as_float((unsigned)(r3 >> 32));
        float2 f0 = __half22float2(v0);
        float2 f1 = __half22float2(v1);
        float2 f2 = __half22float2(v2);
        float2 f3 = __half22float2(v3);
        ax = fmaf(f0.x, w0, ax); ay = fmaf(f0.y, w0, ay);
        ax = fmaf(f1.x, w1, ax); ay = fmaf(f1.y, w1, ay);
        ax = fmaf(f2.x, w2, ax); ay = fmaf(f2.y, w2, ay);
        ax = fmaf(f3.x, w3, ax); ay = fmaf(f3.y, w3, ay);
      }
      for (; e < end; ++e) {
        unsigned long long r = sw[e];
        __half2 vv = y2[(size_t)(unsigned)r * 32 + lane];
        float w = __uint_as_float((unsigned)(r >> 32));
        float2 f = __half22float2(vv);
        ax = fmaf(f.x, w, ax); ay = fmaf(f.y, w, ay);
      }
      invc = 1.0f / fmaxf((float)c, 1.0f);
    }
    aggs[hw][2 * lane + 0] = ax * invc;
    aggs[hw][2 * lane + 1] = ay * invc;
    __syncthreads();

#pragma unroll
    for (int s = 0; s < 2; ++s) {
      int ln = (threadIdx.x >> 6) + s * 4;
      int gn = g * 8 + ln;
      if (gn < n) {
        float a0 = __half2float(tq[(size_t)gn * 64 + j]);
        float a1 = 0.0f, a2 = 0.0f, a3 = 0.0f;
#pragma unroll
        for (int kb = 0; kb < 4; ++kb) {
          float4 v0 = *(const float4*)&aggs[ln][kb * 16 + 0];
          float4 v1 = *(const float4*)&aggs[ln][kb * 16 + 4];
          float4 v2 = *(const float4*)&aggs[ln][kb * 16 + 8];
          float4 v3 = *(const float4*)&aggs[ln][kb * 16 + 12];
          a0 = fmaf(v0.x, wreg[kb * 16 + 0], a0);
          a0 = fmaf(v0.y, wreg[kb * 16 + 1], a0);
          a0 = fmaf(v0.z, wreg[kb * 16 + 2], a0);
          a0 = fmaf(v0.w, wreg[kb * 16 + 3], a0);
          a1 = fmaf(v1.x, wreg[kb * 16 + 4], a1);
          a1 = fmaf(v1.y, wreg[kb * 16 + 5], a1);
          a1 = fmaf(v1.z, wreg[kb * 16 + 6], a1);
          a1 = fmaf(v1.w, wreg[kb * 16 + 7], a1);
          a2 = fmaf(v2.x, wreg[kb * 16 + 8], a2);
          a2 = fmaf(v2.y, wreg[kb * 16 + 9], a2);
          a2 = fmaf(v2.z, wreg[kb * 16 + 10], a2);
          a2 = fmaf(v2.w, wreg[kb * 16 + 11], a2);
          a3 = fmaf(v3.x, wreg[kb * 16 + 12], a3);
          a3 = fmaf(v3.y, wreg[kb * 16 + 13], a3);
          a3 = fmaf(v3.z, wreg[kb * 16 + 14], a3);
          a3 = fmaf(v3.w, wreg[kb * 16 + 15], a3);
        }
        float acc = (a0 + a1) + (a2 + a3);
        float h = fmaxf(acc, 0.0f);
        float ss = h * h;
#pragma unroll
        for (int off = 32; off >= 1; off >>= 1) ss += __shfl_xor(ss, off, 64);
        out[(size_t)gn * 64 + j] = h / fmaxf(sqrtf(ss), 1e-12f);
      }
    }
    __syncthreads();
  }
}

extern "C" void kernel_launch(void* const* d_in, const int* in_sizes, int n_in,
                              void* d_out, int out_size, void* d_ws, size_t ws_size,
                              hipStream_t stream) {
  const float* x  = (const float*)d_in[0];
  const int*   ei = (const int*)d_in[1];
  const float* ew = (const float*)d_in[2];
  const float* Wm = (const float*)d_in[3];
  const float* bm = (const float*)d_in[4];
  const float* Wu = (const float*)d_in[5];
  const float* bu = (const float*)d_in[6];

  int n = in_sizes[0] / DIM;   // 100000
  int E = in_sizes[2];         // 1200000
  const int* srcIdx = ei;
  const int* dstIdx = ei + E;
  int nbuck = (n + NPB - 1) >> LOG_NPB;   // 391

  // workspace (~37.6 MB): y | sw | recS (tq aliases after partB) | dlocS | ...
  __half* y = (__half*)d_ws;                                            // n*64 fp16
  unsigned long long* sw = (unsigned long long*)(y + (size_t)n * DIM);  // E u64
  unsigned long long* recS = sw + E;                                    // nbuck*CAP u64
  unsigned char* dlocS = (unsigned char*)(recS + (size_t)nbuck * CAP);  // nbuck*CAP u8
  int* cnt      = (int*)(dlocS + (size_t)nbuck * CAP);                  // n
  int* rowstart = cnt + n;                                              // n
  int* bucketCur = rowstart + n;                                        // NBUCK_MAX
  int* btotscan  = bucketCur + NBUCK_MAX;                               // NBUCK_MAX
  __half* tq = (__half*)recS;   // alias: recS dead after k_partB

  hipMemsetAsync(bucketCur, 0, NBUCK_MAX * sizeof(int), stream);

  int nblkA = (E + CHUNK - 1) / CHUNK;    // 586
  k_partA<<<nblkA, 256, 0, stream>>>(srcIdx, dstIdx, ew, recS, dlocS, bucketCur, E, nbuck);
  k_scanBk<<<1, 512, 0, stream>>>(bucketCur, btotscan, nbuck);
  k_partB<<<nbuck, 256, 0, stream>>>(recS, dlocS, bucketCur, btotscan, sw, cnt, rowstart, n);

  const int NB = 2048, NW = NB * 4;
  k_msg<<<NB, 256, 0, stream>>>(x, Wm, bm, y, n, NW);
  k_updA<<<NB, 256, 0, stream>>>(x, Wu, bu, tq, n, NW);   // tq overwrites recS
  k_gupd<<<2048, 256, 0, stream>>>(sw, rowstart, cnt, (const __half2*)y, tq, Wu,
                                   (float*)d_out, n);
}

// Round 9
// 258.362 us; speedup vs baseline: 2.7711x; 1.0437x over previous
//
#include <hip/hip_runtime.h>
#include <hip/hip_fp16.h>

// MessagePassingLayer, pull-based CSR build — best-of-each-round assembly:
//  y = relu(x@Wm+bm) per NODE, fp16 (r3);
//  t = x@Wu[0:64]+bu per NODE, fp16, aliases recS (r5 split: wreg[128] spills, 64 ok);
//  partA: 98 dst-buckets of 1024 nodes (write locality: 21 rec/bucket/block),
//         CHUNK=2048 -> 586 blocks (r8 lesson: 293 blocks = latency-starved);
//  partB: per bucket, 1024 THREADS (r7 lesson: 256-thr/98-blk = 3% occupancy,
//         43us of pure latency), LDS count + scan -> cnt/rowstart + binning;
//  gather: half-wave per node, MLP-8 pull (r4 proven; r8 lesson: fusing the
//          update GEMM into it couples gather latency behind barriers, 85us);
//  updB: out = l2norm(relu(t + agg@Wu[64:128])) in-place on d_out (r7 proven).

#define DIM 64
#define NPB 1024            // nodes per bucket
#define LOG_NPB 10
#define NBUCK_MAX 128
#define CAP 16384           // staging capacity per bucket (avg fill 12245)
#define CHUNK 2048          // edges per partA block -> 586 blocks
#define EPT 8               // edges per thread in partA

// ---------------- y = relu(x @ Wm + bm) -> fp16 ----------------
__global__ __launch_bounds__(256) void k_msg(
    const float* __restrict__ x, const float* __restrict__ W,
    const float* __restrict__ b, __half* __restrict__ y, int n, int nwaves) {
  int tid = threadIdx.x;
  int w = tid >> 6, j = tid & 63;
  float wreg[64];
#pragma unroll
  for (int k = 0; k < 64; ++k) wreg[k] = W[k * 64 + j];
  float bj = b[j];
  __shared__ float xs[4][64];
  for (int i = blockIdx.x * 4 + w; i < n; i += nwaves) {
    xs[w][j] = x[(size_t)i * 64 + j];
    float a0 = bj, a1 = 0.0f, a2 = 0.0f, a3 = 0.0f;
#pragma unroll
    for (int kb = 0; kb < 4; ++kb) {
      float4 v0 = *(const float4*)&xs[w][kb * 16 + 0];
      float4 v1 = *(const float4*)&xs[w][kb * 16 + 4];
      float4 v2 = *(const float4*)&xs[w][kb * 16 + 8];
      float4 v3 = *(const float4*)&xs[w][kb * 16 + 12];
      a0 = fmaf(v0.x, wreg[kb * 16 + 0], a0);
      a0 = fmaf(v0.y, wreg[kb * 16 + 1], a0);
      a0 = fmaf(v0.z, wreg[kb * 16 + 2], a0);
      a0 = fmaf(v0.w, wreg[kb * 16 + 3], a0);
      a1 = fmaf(v1.x, wreg[kb * 16 + 4], a1);
      a1 = fmaf(v1.y, wreg[kb * 16 + 5], a1);
      a1 = fmaf(v1.z, wreg[kb * 16 + 6], a1);
      a1 = fmaf(v1.w, wreg[kb * 16 + 7], a1);
      a2 = fmaf(v2.x, wreg[kb * 16 + 8], a2);
      a2 = fmaf(v2.y, wreg[kb * 16 + 9], a2);
      a2 = fmaf(v2.z, wreg[kb * 16 + 10], a2);
      a2 = fmaf(v2.w, wreg[kb * 16 + 11], a2);
      a3 = fmaf(v3.x, wreg[kb * 16 + 12], a3);
      a3 = fmaf(v3.y, wreg[kb * 16 + 13], a3);
      a3 = fmaf(v3.z, wreg[kb * 16 + 14], a3);
      a3 = fmaf(v3.w, wreg[kb * 16 + 15], a3);
    }
    float acc = (a0 + a1) + (a2 + a3);
    y[(size_t)i * 64 + j] = __float2half(fmaxf(acc, 0.0f));
  }
}

// ---------------- t = x @ Wu[0:64] + bu -> fp16 (no relu) ----------------
__global__ __launch_bounds__(256) void k_updA(
    const float* __restrict__ x, const float* __restrict__ W,
    const float* __restrict__ b, __half* __restrict__ tq, int n, int nwaves) {
  int tid = threadIdx.x;
  int w = tid >> 6, j = tid & 63;
  float wreg[64];
#pragma unroll
  for (int k = 0; k < 64; ++k) wreg[k] = W[k * 64 + j];   // rows 0..63 (x-part)
  float bj = b[j];
  __shared__ float xs[4][64];
  for (int i = blockIdx.x * 4 + w; i < n; i += nwaves) {
    xs[w][j] = x[(size_t)i * 64 + j];
    float a0 = bj, a1 = 0.0f, a2 = 0.0f, a3 = 0.0f;
#pragma unroll
    for (int kb = 0; kb < 4; ++kb) {
      float4 v0 = *(const float4*)&xs[w][kb * 16 + 0];
      float4 v1 = *(const float4*)&xs[w][kb * 16 + 4];
      float4 v2 = *(const float4*)&xs[w][kb * 16 + 8];
      float4 v3 = *(const float4*)&xs[w][kb * 16 + 12];
      a0 = fmaf(v0.x, wreg[kb * 16 + 0], a0);
      a0 = fmaf(v0.y, wreg[kb * 16 + 1], a0);
      a0 = fmaf(v0.z, wreg[kb * 16 + 2], a0);
      a0 = fmaf(v0.w, wreg[kb * 16 + 3], a0);
      a1 = fmaf(v1.x, wreg[kb * 16 + 4], a1);
      a1 = fmaf(v1.y, wreg[kb * 16 + 5], a1);
      a1 = fmaf(v1.z, wreg[kb * 16 + 6], a1);
      a1 = fmaf(v1.w, wreg[kb * 16 + 7], a1);
      a2 = fmaf(v2.x, wreg[kb * 16 + 8], a2);
      a2 = fmaf(v2.y, wreg[kb * 16 + 9], a2);
      a2 = fmaf(v2.z, wreg[kb * 16 + 10], a2);
      a2 = fmaf(v2.w, wreg[kb * 16 + 11], a2);
      a3 = fmaf(v3.x, wreg[kb * 16 + 12], a3);
      a3 = fmaf(v3.y, wreg[kb * 16 + 13], a3);
      a3 = fmaf(v3.z, wreg[kb * 16 + 14], a3);
      a3 = fmaf(v3.w, wreg[kb * 16 + 15], a3);
    }
    float acc = (a0 + a1) + (a2 + a3);
    tq[(size_t)i * 64 + j] = __float2half(acc);
  }
}

// ---------------- partA: bucket-partition edges (586 blocks) ----------------
__global__ __launch_bounds__(256) void k_partA(
    const int* __restrict__ src, const int* __restrict__ dst,
    const float* __restrict__ ew,
    unsigned long long* __restrict__ recS, unsigned short* __restrict__ dlocS,
    int* __restrict__ bucketCur, int E, int nbuck) {
  __shared__ int hist[NBUCK_MAX];
  __shared__ int gbase[NBUCK_MAX];
  int t = threadIdx.x;
  int base = blockIdx.x * CHUNK;

  for (int b = t; b < nbuck; b += 256) hist[b] = 0;
  __syncthreads();

  unsigned long long rec[EPT];
  unsigned short dl[EPT];
  short bk[EPT];
#pragma unroll
  for (int i = 0; i < EPT; ++i) {
    int e = base + i * 256 + t;
    if (e < E) {
      int d = dst[e];
      int b = d >> LOG_NPB;
      bk[i] = (short)b;
      dl[i] = (unsigned short)(d & (NPB - 1));
      rec[i] = ((unsigned long long)__float_as_uint(ew[e]) << 32) | (unsigned)src[e];
      atomicAdd(&hist[b], 1);
    } else {
      bk[i] = -1;
    }
  }
  __syncthreads();
  for (int b = t; b < nbuck; b += 256)
    gbase[b] = atomicAdd(&bucketCur[b], hist[b]);
  __syncthreads();
  for (int b = t; b < nbuck; b += 256) hist[b] = 0;  // reuse as local cursor
  __syncthreads();
#pragma unroll
  for (int i = 0; i < EPT; ++i) {
    if (bk[i] >= 0) {
      int b = bk[i];
      int lp = gbase[b] + atomicAdd(&hist[b], 1);
      if (lp < CAP) {                    // paranoia clamp (never hit for uniform dst)
        size_t pos = (size_t)b * CAP + lp;
        recS[pos] = rec[i];
        dlocS[pos] = dl[i];
      }
    }
  }
}

// ---------------- exclusive scan of bucket totals (nbuck <= 128) ----------------
__global__ __launch_bounds__(128) void k_scanBk(const int* __restrict__ bucketCur,
                                                int* __restrict__ btotscan, int nbuck) {
  int tid = threadIdx.x, lane = tid & 63;
  int v = tid < nbuck ? bucketCur[tid] : 0;
  int incl = v;
#pragma unroll
  for (int off = 1; off < 64; off <<= 1) {
    int tt = __shfl_up(incl, off, 64);
    if (lane >= off) incl += tt;
  }
  __shared__ int wt[2];
  if (lane == 63) wt[tid >> 6] = incl;
  __syncthreads();
  int add = (tid >= 64) ? wt[0] : 0;
  if (tid < nbuck) btotscan[tid] = incl - v + add;
}

// ---------------- partB: per-bucket count + scan + bin, 1024 threads ----------------
__global__ __launch_bounds__(1024) void k_partB(
    const unsigned long long* __restrict__ recS, const unsigned short* __restrict__ dlocS,
    const int* __restrict__ bucketCur, const int* __restrict__ btotscan,
    unsigned long long* __restrict__ sw, int* __restrict__ cnt,
    int* __restrict__ rowstart, int n) {
  __shared__ int lcnt[NPB];
  __shared__ int loff[NPB];
  __shared__ int wsum[16];
  int b = blockIdx.x;
  int t = threadIdx.x;
  int m = bucketCur[b];
  if (m > CAP) m = CAP;
  size_t sbase = (size_t)b * CAP;
  int bktbase = btotscan[b];

  lcnt[t] = 0;
  __syncthreads();
  for (int i = t; i < m; i += 1024)
    atomicAdd(&lcnt[dlocS[sbase + i]], 1);
  __syncthreads();

  // exclusive scan of lcnt[0..1023], 1 entry/thread, 16 waves
  int v = lcnt[t];
  int lane = t & 63;
  int incl = v;
#pragma unroll
  for (int off = 1; off < 64; off <<= 1) {
    int tt = __shfl_up(incl, off, 64);
    if (lane >= off) incl += tt;
  }
  if (lane == 63) wsum[t >> 6] = incl;
  __syncthreads();
  int woff = 0;
  for (int q = 0; q < (t >> 6); ++q) woff += wsum[q];
  int excl = incl - v + woff;
  loff[t] = excl;
  int gn = (b << LOG_NPB) + t;
  if (gn < n) {
    cnt[gn] = v;
    rowstart[gn] = bktbase + excl;
  }
  __syncthreads();

  // bin records via LDS cursors; writes stay in bucket's contiguous sw window
  for (int i = t; i < m; i += 1024) {
    int dl = dlocS[sbase + i];
    int p = atomicAdd(&loff[dl], 1);
    sw[bktbase + p] = recS[sbase + i];
  }
}

// ---------------- pull-gather: half-wave per node, MLP-8, fp16 y ----------------
__global__ __launch_bounds__(256) void k_gather(
    const unsigned long long* __restrict__ sw, const int* __restrict__ rowstart,
    const int* __restrict__ cnt, const __half2* __restrict__ y2,
    float* __restrict__ agg, int n) {
  int lane = threadIdx.x & 31;
  int node = (int)((blockIdx.x * (size_t)blockDim.x + threadIdx.x) >> 5);
  if (node >= n) return;
  int c = cnt[node];
  int e = rowstart[node];
  int end = e + c;
  float ax = 0.0f, ay = 0.0f;
  for (; e + 8 <= end; e += 8) {
    unsigned long long r0 = sw[e + 0];
    unsigned long long r1 = sw[e + 1];
    unsigned long long r2 = sw[e + 2];
    unsigned long long r3 = sw[e + 3];
    unsigned long long r4 = sw[e + 4];
    unsigned long long r5 = sw[e + 5];
    unsigned long long r6 = sw[e + 6];
    unsigned long long r7 = sw[e + 7];
    __half2 v0 = y2[(size_t)(unsigned)(r0 & 0x1FFFF) * 32 + lane];
    __half2 v1 = y2[(size_t)(unsigned)(r1 & 0x1FFFF) * 32 + lane];
    __half2 v2 = y2[(size_t)(unsigned)(r2 & 0x1FFFF) * 32 + lane];
    __half2 v3 = y2[(size_t)(unsigned)(r3 & 0x1FFFF) * 32 + lane];
    __half2 v4 = y2[(size_t)(unsigned)(r4 & 0x1FFFF) * 32 + lane];
    __half2 v5 = y2[(size_t)(unsigned)(r5 & 0x1FFFF) * 32 + lane];
    __half2 v6 = y2[(size_t)(unsigned)(r6 & 0x1FFFF) * 32 + lane];
    __half2 v7 = y2[(size_t)(unsigned)(r7 & 0x1FFFF) * 32 + lane];
    float w0 = __uint_as_float((unsigned)(r0 >> 32));
    float w1 = __uint_as_float((unsigned)(r1 >> 32));
    float w2 = __uint_as_float((unsigned)(r2 >> 32));
    float w3 = __uint_as_float((unsigned)(r3 >> 32));
    float w4 = __uint_as_float((unsigned)(r4 >> 32));
    float w5 = __uint_as_float((unsigned)(r5 >> 32));
    float w6 = __uint_as_float((unsigned)(r6 >> 32));
    float w7 = __uint_as_float((unsigned)(r7 >> 32));
    float2 f0 = __half22float2(v0);
    float2 f1 = __half22float2(v1);
    float2 f2 = __half22float2(v2);
    float2 f3 = __half22float2(v3);
    float2 f4 = __half22float2(v4);
    float2 f5 = __half22float2(v5);
    float2 f6 = __half22float2(v6);
    float2 f7 = __half22float2(v7);
    ax = fmaf(f0.x, w0, ax); ay = fmaf(f0.y, w0, ay);
    ax = fmaf(f1.x, w1, ax); ay = fmaf(f1.y, w1, ay);
    ax = fmaf(f2.x, w2, ax); ay = fmaf(f2.y, w2, ay);
    ax = fmaf(f3.x, w3, ax); ay = fmaf(f3.y, w3, ay);
    ax = fmaf(f4.x, w4, ax); ay = fmaf(f4.y, w4, ay);
    ax = fmaf(f5.x, w5, ax); ay = fmaf(f5.y, w5, ay);
    ax = fmaf(f6.x, w6, ax); ay = fmaf(f6.y, w6, ay);
    ax = fmaf(f7.x, w7, ax); ay = fmaf(f7.y, w7, ay);
  }
  for (; e + 4 <= end; e += 4) {
    unsigned long long r0 = sw[e + 0];
    unsigned long long r1 = sw[e + 1];
    unsigned long long r2 = sw[e + 2];
    unsigned long long r3 = sw[e + 3];
    __half2 v0 = y2[(size_t)(unsigned)(r0 & 0x1FFFF) * 32 + lane];
    __half2 v1 = y2[(size_t)(unsigned)(r1 & 0x1FFFF) * 32 + lane];
    __half2 v2 = y2[(size_t)(unsigned)(r2 & 0x1FFFF) * 32 + lane];
    __half2 v3 = y2[(size_t)(unsigned)(r3 & 0x1FFFF) * 32 + lane];
    float w0 = __uint_as_float((unsigned)(r0 >> 32));
    float w1 = __uint_as_float((unsigned)(r1 >> 32));
    float w2 = __uint_as_float((unsigned)(r2 >> 32));
    float w3 = __uint_as_float((unsigned)(r3 >> 32));
    float2 f0 = __half22float2(v0);
    float2 f1 = __half22float2(v1);
    float2 f2 = __half22float2(v2);
    float2 f3 = __half22float2(v3);
    ax = fmaf(f0.x, w0, ax); ay = fmaf(f0.y, w0, ay);
    ax = fmaf(f1.x, w1, ax); ay = fmaf(f1.y, w1, ay);
    ax = fmaf(f2.x, w2, ax); ay = fmaf(f2.y, w2, ay);
    ax = fmaf(f3.x, w3, ax); ay = fmaf(f3.y, w3, ay);
  }
  for (; e < end; ++e) {
    unsigned long long r = sw[e];
    __half2 vv = y2[(size_t)(unsigned)(r & 0x1FFFF) * 32 + lane];
    float w = __uint_as_float((unsigned)(r >> 32));
    float2 f = __half22float2(vv);
    ax = fmaf(f.x, w, ax); ay = fmaf(f.y, w, ay);
  }
  float invd = 1.0f / fmaxf((float)c, 1.0f);
  float2 o; o.x = ax * invd; o.y = ay * invd;
  *(float2*)&agg[(size_t)node * 64 + lane * 2] = o;
}

// ---------------- updB: out = l2norm(relu(t + agg @ Wu[64:128])) ----------------
__global__ __launch_bounds__(256) void k_updB(
    const __half* __restrict__ tq, float* io /* agg in, out */,
    const float* __restrict__ W, int n, int nwaves) {
  int tid = threadIdx.x;
  int w = tid >> 6, j = tid & 63;
  float wreg[64];
#pragma unroll
  for (int k = 0; k < 64; ++k) wreg[k] = W[(64 + k) * 64 + j];  // agg-part rows
  __shared__ float xs[4][64];
  for (int i = blockIdx.x * 4 + w; i < n; i += nwaves) {
    xs[w][j] = io[(size_t)i * 64 + j];     // agg row (mean already applied)
    float a0 = __half2float(tq[(size_t)i * 64 + j]);
    float a1 = 0.0f, a2 = 0.0f, a3 = 0.0f;
#pragma unroll
    for (int kb = 0; kb < 4; ++kb) {
      float4 v0 = *(const float4*)&xs[w][kb * 16 + 0];
      float4 v1 = *(const float4*)&xs[w][kb * 16 + 4];
      float4 v2 = *(const float4*)&xs[w][kb * 16 + 8];
      float4 v3 = *(const float4*)&xs[w][kb * 16 + 12];
      a0 = fmaf(v0.x, wreg[kb * 16 + 0], a0);
      a0 = fmaf(v0.y, wreg[kb * 16 + 1], a0);
      a0 = fmaf(v0.z, wreg[kb * 16 + 2], a0);
      a0 = fmaf(v0.w, wreg[kb * 16 + 3], a0);
      a1 = fmaf(v1.x, wreg[kb * 16 + 4], a1);
      a1 = fmaf(v1.y, wreg[kb * 16 + 5], a1);
      a1 = fmaf(v1.z, wreg[kb * 16 + 6], a1);
      a1 = fmaf(v1.w, wreg[kb * 16 + 7], a1);
      a2 = fmaf(v2.x, wreg[kb * 16 + 8], a2);
      a2 = fmaf(v2.y, wreg[kb * 16 + 9], a2);
      a2 = fmaf(v2.z, wreg[kb * 16 + 10], a2);
      a2 = fmaf(v2.w, wreg[kb * 16 + 11], a2);
      a3 = fmaf(v3.x, wreg[kb * 16 + 12], a3);
      a3 = fmaf(v3.y, wreg[kb * 16 + 13], a3);
      a3 = fmaf(v3.z, wreg[kb * 16 + 14], a3);
      a3 = fmaf(v3.w, wreg[kb * 16 + 15], a3);
    }
    float acc = (a0 + a1) + (a2 + a3);
    float h = fmaxf(acc, 0.0f);
    float ss = h * h;
#pragma unroll
    for (int off = 32; off >= 1; off >>= 1) ss += __shfl_xor(ss, off, 64);
    io[(size_t)i * 64 + j] = h / fmaxf(sqrtf(ss), 1e-12f);
  }
}

extern "C" void kernel_launch(void* const* d_in, const int* in_sizes, int n_in,
                              void* d_out, int out_size, void* d_ws, size_t ws_size,
                              hipStream_t stream) {
  const float* x  = (const float*)d_in[0];
  const int*   ei = (const int*)d_in[1];
  const float* ew = (const float*)d_in[2];
  const float* Wm = (const float*)d_in[3];
  const float* bm = (const float*)d_in[4];
  const float* Wu = (const float*)d_in[5];
  const float* bu = (const float*)d_in[6];

  int n = in_sizes[0] / DIM;   // 100000
  int E = in_sizes[2];         // 1200000
  const int* srcIdx = ei;
  const int* dstIdx = ei + E;
  int nbuck = (n + NPB - 1) >> LOG_NPB;   // 98

  // workspace (~39.3 MB): y | sw | recS (tq aliases after partB) | dlocS | ...
  __half* y = (__half*)d_ws;                                            // n*64 fp16
  unsigned long long* sw = (unsigned long long*)(y + (size_t)n * DIM);  // E u64
  unsigned long long* recS = sw + E;                                    // nbuck*CAP u64
  unsigned short* dlocS = (unsigned short*)(recS + (size_t)nbuck * CAP);// nbuck*CAP u16
  int* cnt      = (int*)(dlocS + (size_t)nbuck * CAP);                  // n
  int* rowstart = cnt + n;                                              // n
  int* bucketCur = rowstart + n;                                        // NBUCK_MAX
  int* btotscan  = bucketCur + NBUCK_MAX;                               // NBUCK_MAX
  __half* tq = (__half*)recS;   // alias: recS dead after k_partB (12.8MB fits)

  hipMemsetAsync(bucketCur, 0, NBUCK_MAX * sizeof(int), stream);

  int nblkA = (E + CHUNK - 1) / CHUNK;    // 586
  k_partA<<<nblkA, 256, 0, stream>>>(srcIdx, dstIdx, ew, recS, dlocS, bucketCur, E, nbuck);
  k_scanBk<<<1, 128, 0, stream>>>(bucketCur, btotscan, nbuck);
  k_partB<<<nbuck, 1024, 0, stream>>>(recS, dlocS, bucketCur, btotscan, sw, cnt, rowstart, n);

  const int NB = 2048, NW = NB * 4;
  k_msg<<<NB, 256, 0, stream>>>(x, Wm, bm, y, n, NW);
  k_updA<<<NB, 256, 0, stream>>>(x, Wu, bu, tq, n, NW);   // tq overwrites recS
  k_gather<<<(n + 7) / 8, 256, 0, stream>>>(sw, rowstart, cnt, (const __half2*)y,
                                            (float*)d_out, n);
  k_updB<<<NB, 256, 0, stream>>>(tq, (float*)d_out, Wu, n, NW);
}

// Round 10
// 201.936 us; speedup vs baseline: 3.5454x; 1.2794x over previous
//
#include <hip/hip_runtime.h>
#include <hip/hip_fp16.h>

// MessagePassingLayer, pull-based CSR + MFMA node GEMMs:
//  mfmaA: FUSED y=relu(x@Wm+bm) and tq=x@Wu[0:64]+bu via mfma_f32_16x16x32_f16
//         (one pass over x; wave = 16-row tile; k-slot bijection identical for
//         A and B frags so exact hw k-map is irrelevant; C/D map m89-verified);
//  partA: 98 dst-buckets of 1024 nodes, CHUNK=2048 (586 blocks);
//  partB: 1024 threads/bucket, inline bucket-prefix (scanBk kernel deleted);
//  gather: half-wave per node, MLP-8 pull of y[src]*w -> agg f32 in d_out;
//  updB2: MFMA h=relu(tq + agg@Wu[64:128]) + 16-lane shfl L2-norm, in-place.

#define DIM 64
#define NPB 1024
#define LOG_NPB 10
#define NBUCK_MAX 128
#define CAP 16384
#define CHUNK 2048
#define EPT 8

typedef _Float16 half8 __attribute__((ext_vector_type(8)));
typedef float f32x4 __attribute__((ext_vector_type(4)));

// ---------------- fused node GEMMs: y = relu(x@Wm+bm), tq = x@Wu_top+bu ----------------
__global__ __launch_bounds__(256) void k_mfmaA(
    const float* __restrict__ x, const float* __restrict__ Wm,
    const float* __restrict__ bm, const float* __restrict__ Wu,
    const float* __restrict__ bu, __half* __restrict__ y,
    __half* __restrict__ tq, int n) {
  int l = threadIdx.x & 63;
  int wv = threadIdx.x >> 6;
  int r = l & 15, g = l >> 4;

  // B-frags: col = ct*16+r, k = ks*32 + g*8 + j  (same bijection as A)
  half8 Bm[2][4], Bu[2][4];
#pragma unroll
  for (int ks = 0; ks < 2; ++ks)
#pragma unroll
    for (int ct = 0; ct < 4; ++ct) {
      int c = ct * 16 + r;
#pragma unroll
      for (int j = 0; j < 8; ++j) {
        int k = ks * 32 + g * 8 + j;
        Bm[ks][ct][j] = (_Float16)Wm[k * 64 + c];
        Bu[ks][ct][j] = (_Float16)Wu[k * 64 + c];
      }
    }
  float bmv[4], buv[4];
#pragma unroll
  for (int ct = 0; ct < 4; ++ct) { bmv[ct] = bm[ct * 16 + r]; buv[ct] = bu[ct * 16 + r]; }

  int ntiles = (n + 15) >> 4;
  int tile = blockIdx.x * 4 + wv;
  if (tile >= ntiles) return;
  int row0 = tile << 4;

  // A-frags: row = row0+r, k = ks*32 + g*8 + j (two float4 loads + cvt)
  int arow = row0 + r; if (arow >= n) arow = n - 1;
  const float* xr = x + (size_t)arow * 64;
  half8 A[2];
#pragma unroll
  for (int ks = 0; ks < 2; ++ks) {
    float4 v0 = *(const float4*)(xr + ks * 32 + g * 8);
    float4 v1 = *(const float4*)(xr + ks * 32 + g * 8 + 4);
    A[ks][0] = (_Float16)v0.x; A[ks][1] = (_Float16)v0.y;
    A[ks][2] = (_Float16)v0.z; A[ks][3] = (_Float16)v0.w;
    A[ks][4] = (_Float16)v1.x; A[ks][5] = (_Float16)v1.y;
    A[ks][6] = (_Float16)v1.z; A[ks][7] = (_Float16)v1.w;
  }

  f32x4 Dm[4], Du[4];
#pragma unroll
  for (int ct = 0; ct < 4; ++ct)
#pragma unroll
    for (int q = 0; q < 4; ++q) { Dm[ct][q] = bmv[ct]; Du[ct][q] = buv[ct]; }

#pragma unroll
  for (int ks = 0; ks < 2; ++ks)
#pragma unroll
    for (int ct = 0; ct < 4; ++ct) {
      Dm[ct] = __builtin_amdgcn_mfma_f32_16x16x32_f16(A[ks], Bm[ks][ct], Dm[ct], 0, 0, 0);
      Du[ct] = __builtin_amdgcn_mfma_f32_16x16x32_f16(A[ks], Bu[ks][ct], Du[ct], 0, 0, 0);
    }

  // C/D: col = ct*16 + (lane&15), row = (lane>>4)*4 + q   [m89-verified]
#pragma unroll
  for (int q = 0; q < 4; ++q) {
    int row = row0 + g * 4 + q;
    if (row < n) {
#pragma unroll
      for (int ct = 0; ct < 4; ++ct) {
        y[(size_t)row * 64 + ct * 16 + r]  = __float2half(fmaxf(Dm[ct][q], 0.0f));
        tq[(size_t)row * 64 + ct * 16 + r] = __float2half(Du[ct][q]);
      }
    }
  }
}

// ---------------- partA: bucket-partition edges (586 blocks) ----------------
__global__ __launch_bounds__(256) void k_partA(
    const int* __restrict__ src, const int* __restrict__ dst,
    const float* __restrict__ ew,
    unsigned long long* __restrict__ recS, unsigned short* __restrict__ dlocS,
    int* __restrict__ bucketCur, int E, int nbuck) {
  __shared__ int hist[NBUCK_MAX];
  __shared__ int gbase[NBUCK_MAX];
  int t = threadIdx.x;
  int base = blockIdx.x * CHUNK;

  for (int b = t; b < nbuck; b += 256) hist[b] = 0;
  __syncthreads();

  unsigned long long rec[EPT];
  unsigned short dl[EPT];
  short bk[EPT];
#pragma unroll
  for (int i = 0; i < EPT; ++i) {
    int e = base + i * 256 + t;
    if (e < E) {
      int d = dst[e];
      int b = d >> LOG_NPB;
      bk[i] = (short)b;
      dl[i] = (unsigned short)(d & (NPB - 1));
      rec[i] = ((unsigned long long)__float_as_uint(ew[e]) << 32) | (unsigned)src[e];
      atomicAdd(&hist[b], 1);
    } else {
      bk[i] = -1;
    }
  }
  __syncthreads();
  for (int b = t; b < nbuck; b += 256)
    gbase[b] = atomicAdd(&bucketCur[b], hist[b]);
  __syncthreads();
  for (int b = t; b < nbuck; b += 256) hist[b] = 0;
  __syncthreads();
#pragma unroll
  for (int i = 0; i < EPT; ++i) {
    if (bk[i] >= 0) {
      int b = bk[i];
      int lp = gbase[b] + atomicAdd(&hist[b], 1);
      if (lp < CAP) {
        size_t pos = (size_t)b * CAP + lp;
        recS[pos] = rec[i];
        dlocS[pos] = dl[i];
      }
    }
  }
}

// ---------------- partB: per-bucket count + scan + bin, inline bucket-prefix ----------------
__global__ __launch_bounds__(1024) void k_partB(
    const unsigned long long* __restrict__ recS, const unsigned short* __restrict__ dlocS,
    const int* __restrict__ bucketCur,
    unsigned long long* __restrict__ sw, int* __restrict__ cnt,
    int* __restrict__ rowstart, int n) {
  __shared__ int lcnt[NPB];
  __shared__ int loff[NPB];
  __shared__ int wsum[16];
  int b = blockIdx.x;
  int t = threadIdx.x;
  int m = bucketCur[b];
  if (m > CAP) m = CAP;
  size_t sbase = (size_t)b * CAP;
  int bktbase = 0;
  for (int q = 0; q < b; ++q) bktbase += bucketCur[q];   // uniform scalar loop

  lcnt[t] = 0;
  __syncthreads();
  for (int i = t; i < m; i += 1024)
    atomicAdd(&lcnt[dlocS[sbase + i]], 1);
  __syncthreads();

  int v = lcnt[t];
  int lane = t & 63;
  int incl = v;
#pragma unroll
  for (int off = 1; off < 64; off <<= 1) {
    int tt = __shfl_up(incl, off, 64);
    if (lane >= off) incl += tt;
  }
  if (lane == 63) wsum[t >> 6] = incl;
  __syncthreads();
  int woff = 0;
  for (int q = 0; q < (t >> 6); ++q) woff += wsum[q];
  int excl = incl - v + woff;
  loff[t] = excl;
  int gn = (b << LOG_NPB) + t;
  if (gn < n) {
    cnt[gn] = v;
    rowstart[gn] = bktbase + excl;
  }
  __syncthreads();

  for (int i = t; i < m; i += 1024) {
    int dl = dlocS[sbase + i];
    int p = atomicAdd(&loff[dl], 1);
    sw[bktbase + p] = recS[sbase + i];
  }
}

// ---------------- pull-gather: half-wave per node, MLP-8, fp16 y ----------------
__global__ __launch_bounds__(256) void k_gather(
    const unsigned long long* __restrict__ sw, const int* __restrict__ rowstart,
    const int* __restrict__ cnt, const __half2* __restrict__ y2,
    float* __restrict__ agg, int n) {
  int lane = threadIdx.x & 31;
  int node = (int)((blockIdx.x * (size_t)blockDim.x + threadIdx.x) >> 5);
  if (node >= n) return;
  int c = cnt[node];
  int e = rowstart[node];
  int end = e + c;
  float ax = 0.0f, ay = 0.0f;
  for (; e + 8 <= end; e += 8) {
    unsigned long long r0 = sw[e + 0];
    unsigned long long r1 = sw[e + 1];
    unsigned long long r2 = sw[e + 2];
    unsigned long long r3 = sw[e + 3];
    unsigned long long r4 = sw[e + 4];
    unsigned long long r5 = sw[e + 5];
    unsigned long long r6 = sw[e + 6];
    unsigned long long r7 = sw[e + 7];
    __half2 v0 = y2[(size_t)(unsigned)(r0 & 0xFFFFFFFFu) * 32 + lane];
    __half2 v1 = y2[(size_t)(unsigned)(r1 & 0xFFFFFFFFu) * 32 + lane];
    __half2 v2 = y2[(size_t)(unsigned)(r2 & 0xFFFFFFFFu) * 32 + lane];
    __half2 v3 = y2[(size_t)(unsigned)(r3 & 0xFFFFFFFFu) * 32 + lane];
    __half2 v4 = y2[(size_t)(unsigned)(r4 & 0xFFFFFFFFu) * 32 + lane];
    __half2 v5 = y2[(size_t)(unsigned)(r5 & 0xFFFFFFFFu) * 32 + lane];
    __half2 v6 = y2[(size_t)(unsigned)(r6 & 0xFFFFFFFFu) * 32 + lane];
    __half2 v7 = y2[(size_t)(unsigned)(r7 & 0xFFFFFFFFu) * 32 + lane];
    float w0 = __uint_as_float((unsigned)(r0 >> 32));
    float w1 = __uint_as_float((unsigned)(r1 >> 32));
    float w2 = __uint_as_float((unsigned)(r2 >> 32));
    float w3 = __uint_as_float((unsigned)(r3 >> 32));
    float w4 = __uint_as_float((unsigned)(r4 >> 32));
    float w5 = __uint_as_float((unsigned)(r5 >> 32));
    float w6 = __uint_as_float((unsigned)(r6 >> 32));
    float w7 = __uint_as_float((unsigned)(r7 >> 32));
    float2 f0 = __half22float2(v0);
    float2 f1 = __half22float2(v1);
    float2 f2 = __half22float2(v2);
    float2 f3 = __half22float2(v3);
    float2 f4 = __half22float2(v4);
    float2 f5 = __half22float2(v5);
    float2 f6 = __half22float2(v6);
    float2 f7 = __half22float2(v7);
    ax = fmaf(f0.x, w0, ax); ay = fmaf(f0.y, w0, ay);
    ax = fmaf(f1.x, w1, ax); ay = fmaf(f1.y, w1, ay);
    ax = fmaf(f2.x, w2, ax); ay = fmaf(f2.y, w2, ay);
    ax = fmaf(f3.x, w3, ax); ay = fmaf(f3.y, w3, ay);
    ax = fmaf(f4.x, w4, ax); ay = fmaf(f4.y, w4, ay);
    ax = fmaf(f5.x, w5, ax); ay = fmaf(f5.y, w5, ay);
    ax = fmaf(f6.x, w6, ax); ay = fmaf(f6.y, w6, ay);
    ax = fmaf(f7.x, w7, ax); ay = fmaf(f7.y, w7, ay);
  }
  for (; e + 4 <= end; e += 4) {
    unsigned long long r0 = sw[e + 0];
    unsigned long long r1 = sw[e + 1];
    unsigned long long r2 = sw[e + 2];
    unsigned long long r3 = sw[e + 3];
    __half2 v0 = y2[(size_t)(unsigned)(r0 & 0xFFFFFFFFu) * 32 + lane];
    __half2 v1 = y2[(size_t)(unsigned)(r1 & 0xFFFFFFFFu) * 32 + lane];
    __half2 v2 = y2[(size_t)(unsigned)(r2 & 0xFFFFFFFFu) * 32 + lane];
    __half2 v3 = y2[(size_t)(unsigned)(r3 & 0xFFFFFFFFu) * 32 + lane];
    float w0 = __uint_as_float((unsigned)(r0 >> 32));
    float w1 = __uint_as_float((unsigned)(r1 >> 32));
    float w2 = __uint_as_float((unsigned)(r2 >> 32));
    float w3 = __uint_as_float((unsigned)(r3 >> 32));
    float2 f0 = __half22float2(v0);
    float2 f1 = __half22float2(v1);
    float2 f2 = __half22float2(v2);
    float2 f3 = __half22float2(v3);
    ax = fmaf(f0.x, w0, ax); ay = fmaf(f0.y, w0, ay);
    ax = fmaf(f1.x, w1, ax); ay = fmaf(f1.y, w1, ay);
    ax = fmaf(f2.x, w2, ax); ay = fmaf(f2.y, w2, ay);
    ax = fmaf(f3.x, w3, ax); ay = fmaf(f3.y, w3, ay);
  }
  for (; e < end; ++e) {
    unsigned long long r = sw[e];
    __half2 vv = y2[(size_t)(unsigned)(r & 0xFFFFFFFFu) * 32 + lane];
    float w = __uint_as_float((unsigned)(r >> 32));
    float2 f = __half22float2(vv);
    ax = fmaf(f.x, w, ax); ay = fmaf(f.y, w, ay);
  }
  float invd = 1.0f / fmaxf((float)c, 1.0f);
  float2 o; o.x = ax * invd; o.y = ay * invd;
  *(float2*)&agg[(size_t)node * 64 + lane * 2] = o;
}

// ---------------- MFMA updB: out = l2norm(relu(tq + agg@Wu[64:128])) in-place ----------------
__global__ __launch_bounds__(256) void k_updB2(
    const float* __restrict__ agg /* == out (d_out) */,
    const __half* __restrict__ tq, const float* __restrict__ Wu,
    float* __restrict__ out, int n) {
  int l = threadIdx.x & 63;
  int wv = threadIdx.x >> 6;
  int r = l & 15, g = l >> 4;

  half8 B2[2][4];
#pragma unroll
  for (int ks = 0; ks < 2; ++ks)
#pragma unroll
    for (int ct = 0; ct < 4; ++ct) {
      int c = ct * 16 + r;
#pragma unroll
      for (int j = 0; j < 8; ++j) {
        int k = 64 + ks * 32 + g * 8 + j;     // agg-part rows of Wu
        B2[ks][ct][j] = (_Float16)Wu[k * 64 + c];
      }
    }

  int ntiles = (n + 15) >> 4;
  int tile = blockIdx.x * 4 + wv;
  if (tile >= ntiles) return;
  int row0 = tile << 4;

  int arow = row0 + r; if (arow >= n) arow = n - 1;
  const float* ar = agg + (size_t)arow * 64;
  half8 A[2];
#pragma unroll
  for (int ks = 0; ks < 2; ++ks) {
    float4 v0 = *(const float4*)(ar + ks * 32 + g * 8);
    float4 v1 = *(const float4*)(ar + ks * 32 + g * 8 + 4);
    A[ks][0] = (_Float16)v0.x; A[ks][1] = (_Float16)v0.y;
    A[ks][2] = (_Float16)v0.z; A[ks][3] = (_Float16)v0.w;
    A[ks][4] = (_Float16)v1.x; A[ks][5] = (_Float16)v1.y;
    A[ks][6] = (_Float16)v1.z; A[ks][7] = (_Float16)v1.w;
  }

  // acc init = tq at each output slot (row = g*4+q, col = ct*16+r)
  f32x4 D[4];
#pragma unroll
  for (int ct = 0; ct < 4; ++ct)
#pragma unroll
    for (int q = 0; q < 4; ++q) {
      int row = row0 + g * 4 + q;
      D[ct][q] = (row < n) ? __half2float(tq[(size_t)row * 64 + ct * 16 + r]) : 0.0f;
    }

#pragma unroll
  for (int ks = 0; ks < 2; ++ks)
#pragma unroll
    for (int ct = 0; ct < 4; ++ct)
      D[ct] = __builtin_amdgcn_mfma_f32_16x16x32_f16(A[ks], B2[ks][ct], D[ct], 0, 0, 0);

#pragma unroll
  for (int q = 0; q < 4; ++q) {
    float h0 = fmaxf(D[0][q], 0.0f);
    float h1 = fmaxf(D[1][q], 0.0f);
    float h2 = fmaxf(D[2][q], 0.0f);
    float h3 = fmaxf(D[3][q], 0.0f);
    float ss = h0 * h0 + h1 * h1 + h2 * h2 + h3 * h3;
#pragma unroll
    for (int off = 1; off < 16; off <<= 1) ss += __shfl_xor(ss, off, 64);
    float inv = 1.0f / fmaxf(sqrtf(ss), 1e-12f);
    int row = row0 + g * 4 + q;
    if (row < n) {
      out[(size_t)row * 64 + 0 * 16 + r] = h0 * inv;
      out[(size_t)row * 64 + 1 * 16 + r] = h1 * inv;
      out[(size_t)row * 64 + 2 * 16 + r] = h2 * inv;
      out[(size_t)row * 64 + 3 * 16 + r] = h3 * inv;
    }
  }
}

extern "C" void kernel_launch(void* const* d_in, const int* in_sizes, int n_in,
                              void* d_out, int out_size, void* d_ws, size_t ws_size,
                              hipStream_t stream) {
  const float* x  = (const float*)d_in[0];
  const int*   ei = (const int*)d_in[1];
  const float* ew = (const float*)d_in[2];
  const float* Wm = (const float*)d_in[3];
  const float* bm = (const float*)d_in[4];
  const float* Wu = (const float*)d_in[5];
  const float* bu = (const float*)d_in[6];

  int n = in_sizes[0] / DIM;   // 100000
  int E = in_sizes[2];         // 1200000
  const int* srcIdx = ei;
  const int* dstIdx = ei + E;
  int nbuck = (n + NPB - 1) >> LOG_NPB;   // 98

  // workspace (~39.3 MB): y | sw | recS (tq aliases after partB) | dlocS | ...
  __half* y = (__half*)d_ws;                                            // n*64 fp16
  unsigned long long* sw = (unsigned long long*)(y + (size_t)n * DIM);  // E u64
  unsigned long long* recS = sw + E;                                    // nbuck*CAP u64
  unsigned short* dlocS = (unsigned short*)(recS + (size_t)nbuck * CAP);// nbuck*CAP u16
  int* cnt      = (int*)(dlocS + (size_t)nbuck * CAP);                  // n
  int* rowstart = cnt + n;                                              // n
  int* bucketCur = rowstart + n;                                        // NBUCK_MAX
  __half* tq = (__half*)recS;   // alias: recS dead after k_partB (12.85MB >= 12.8)

  hipMemsetAsync(bucketCur, 0, NBUCK_MAX * sizeof(int), stream);

  int nblkA = (E + CHUNK - 1) / CHUNK;    // 586
  k_partA<<<nblkA, 256, 0, stream>>>(srcIdx, dstIdx, ew, recS, dlocS, bucketCur, E, nbuck);
  k_partB<<<nbuck, 1024, 0, stream>>>(recS, dlocS, bucketCur, sw, cnt, rowstart, n);

  int ntiles = (n + 15) >> 4;
  int nblkG = (ntiles + 3) / 4;           // 1563
  k_mfmaA<<<nblkG, 256, 0, stream>>>(x, Wm, bm, Wu, bu, y, tq, n);  // tq overwrites recS
  k_gather<<<(n + 7) / 8, 256, 0, stream>>>(sw, rowstart, cnt, (const __half2*)y,
                                            (float*)d_out, n);
  k_updB2<<<nblkG, 256, 0, stream>>>((const float*)d_out, tq, Wu, (float*)d_out, n);
}